// Round 5
// baseline (1068.290 us; speedup 1.0000x reference)
//
#include <hip/hip_runtime.h>
#include <math.h>

typedef _Float16 f16;
typedef f16 f16x2 __attribute__((ext_vector_type(2)));
typedef f16 f16x8 __attribute__((ext_vector_type(8)));
typedef float f32x4 __attribute__((ext_vector_type(4)));

template <int V> struct VecT;
template <> struct VecT<2> { using T = f16 __attribute__((ext_vector_type(2))); };
template <> struct VecT<8> { using T = f16 __attribute__((ext_vector_type(8))); };

// ---------------------------------------------------------------------------
// CSR build: histogram of dst -> exclusive scan -> fill permutation
// Edge id space: [0, E) = real edges, [E, E+N) = self loops (src=dst=id-E)
// ---------------------------------------------------------------------------

__global__ void k_count(const int* __restrict__ dstArr, int* __restrict__ cnt,
                        int E, int Et) {
  int i = blockIdx.x * blockDim.x + threadIdx.x;
  if (i >= Et) return;
  int d = (i < E) ? dstArr[i] : (i - E);
  atomicAdd(&cnt[d], 1);
}

__global__ __launch_bounds__(1024) void k_scan(const int* __restrict__ cnt,
                                               int* __restrict__ row_ptr, int n) {
  __shared__ int part[1024];
  int t = threadIdx.x;
  int items = (n + 1023) / 1024;
  int base = t * items;
  int local[64];
  int s = 0;
  for (int j = 0; j < items; ++j) {
    int idx = base + j;
    int v = (idx < n) ? cnt[idx] : 0;
    local[j] = s;
    s += v;
  }
  part[t] = s;
  __syncthreads();
  for (int off = 1; off < 1024; off <<= 1) {
    int v = (t >= off) ? part[t - off] : 0;
    __syncthreads();
    part[t] += v;
    __syncthreads();
  }
  int excl = (t == 0) ? 0 : part[t - 1];
  for (int j = 0; j < items; ++j) {
    int idx = base + j;
    if (idx < n) row_ptr[idx] = excl + local[j];
  }
  if (t == 1023) row_ptr[n] = part[1023];
}

__global__ void k_copy(const int* __restrict__ src, int* __restrict__ dst, int n) {
  int i = blockIdx.x * blockDim.x + threadIdx.x;
  if (i < n) dst[i] = src[i];
}

__global__ void k_fill(const int* __restrict__ dstArr, int* __restrict__ cursor,
                       int* __restrict__ perm, int E, int Et) {
  int i = blockIdx.x * blockDim.x + threadIdx.x;
  if (i >= Et) return;
  int d = (i < E) ? dstArr[i] : (i - E);
  int pos = atomicAdd(&cursor[d], 1);
  perm[pos] = i;
}

// ---------------------------------------------------------------------------
// fp32 -> fp16 conversion (vectorized by 4; n must be multiple of 4)
// ---------------------------------------------------------------------------
__global__ void k_f2h(const float* __restrict__ in, f16* __restrict__ out, int n4) {
  int i = blockIdx.x * blockDim.x + threadIdx.x;
  if (i >= n4) return;
  float4 v = ((const float4*)in)[i];
  union { f16 h[4]; double d; } u;
  u.h[0] = (f16)v.x; u.h[1] = (f16)v.y; u.h[2] = (f16)v.z; u.h[3] = (f16)v.w;
  ((double*)out)[i] = u.d;
}

// ---------------------------------------------------------------------------
// HGEMM (fp16 MFMA, fp32 accumulate): C[M,Nn] = A[M,K] @ B[Nn,K]^T
// 128x128 tile, BK=32, 256 thr = 4 waves, wave = 64x64 quadrant (4x4 MFMAs).
// Requires: Nn % 128 == 0, K % 32 == 0. M guarded. fp16 C output.
// ---------------------------------------------------------------------------
#define LDSW 40
__global__ __launch_bounds__(256) void k_hgemm_nt(
    const f16* __restrict__ A, const f16* __restrict__ B,
    f16* __restrict__ C, int M, int Nn, int K) {
  __shared__ f16 As[128 * LDSW];
  __shared__ f16 Bs[128 * LDSW];
  int tid = threadIdx.x;
  int wave = tid >> 6, lane = tid & 63;
  int quad = lane >> 4, l16 = lane & 15;
  int m0 = blockIdx.y * 128, n0 = blockIdx.x * 128;
  int wm = (wave & 1) * 64, wn = (wave >> 1) * 64;

  int srow = tid >> 2;
  int scol = (tid & 3) * 8;
  int ar0 = m0 + srow;       if (ar0 >= M) ar0 = M - 1;
  int ar1 = m0 + srow + 64;  if (ar1 >= M) ar1 = M - 1;
  const f16* Ap0 = A + (size_t)ar0 * K + scol;
  const f16* Ap1 = A + (size_t)ar1 * K + scol;
  const f16* Bp0 = B + (size_t)(n0 + srow) * K + scol;
  const f16* Bp1 = B + (size_t)(n0 + srow + 64) * K + scol;
  f16* Asw0 = &As[srow * LDSW + scol];
  f16* Asw1 = &As[(srow + 64) * LDSW + scol];
  f16* Bsw0 = &Bs[srow * LDSW + scol];
  f16* Bsw1 = &Bs[(srow + 64) * LDSW + scol];

  const f16* Ard[4];
  const f16* Brd[4];
#pragma unroll
  for (int i = 0; i < 4; ++i) {
    Ard[i] = &As[(wm + i * 16 + l16) * LDSW + quad * 8];
    Brd[i] = &Bs[(wn + i * 16 + l16) * LDSW + quad * 8];
  }

  f32x4 acc[4][4];
#pragma unroll
  for (int i = 0; i < 4; ++i)
#pragma unroll
    for (int j = 0; j < 4; ++j) acc[i][j] = (f32x4)(0.f);

  for (int k0 = 0; k0 < K; k0 += 32) {
    f16x8 av0 = *(const f16x8*)(Ap0 + k0);
    f16x8 av1 = *(const f16x8*)(Ap1 + k0);
    f16x8 bv0 = *(const f16x8*)(Bp0 + k0);
    f16x8 bv1 = *(const f16x8*)(Bp1 + k0);
    __syncthreads();
    *(f16x8*)Asw0 = av0;
    *(f16x8*)Asw1 = av1;
    *(f16x8*)Bsw0 = bv0;
    *(f16x8*)Bsw1 = bv1;
    __syncthreads();
    f16x8 af[4], bf[4];
#pragma unroll
    for (int i = 0; i < 4; ++i) af[i] = *(const f16x8*)Ard[i];
#pragma unroll
    for (int j = 0; j < 4; ++j) bf[j] = *(const f16x8*)Brd[j];
#pragma unroll
    for (int i = 0; i < 4; ++i)
#pragma unroll
      for (int j = 0; j < 4; ++j)
        acc[i][j] = __builtin_amdgcn_mfma_f32_16x16x32_f16(af[i], bf[j], acc[i][j], 0, 0, 0);
  }

#pragma unroll
  for (int i = 0; i < 4; ++i) {
#pragma unroll
    for (int r = 0; r < 4; ++r) {
      int m = m0 + wm + i * 16 + quad * 4 + r;
      if (m < M) {
        f16* Cp = C + (size_t)m * Nn + n0 + wn + l16;
#pragma unroll
        for (int j = 0; j < 4; ++j) Cp[j * 16] = (f16)acc[i][j][r];
      }
    }
  }
}

// ---------------------------------------------------------------------------
// Per-node attention scalars from fp16 h: s[n,h] = <h[n,h,:], a_src[h,:]>.
// One wave per (node, head); Cc assumed even.
// ---------------------------------------------------------------------------
__global__ void k_attn_sd(const f16* __restrict__ h,
                          const float* __restrict__ a_src,
                          const float* __restrict__ a_dst,
                          float* __restrict__ sArr, float* __restrict__ dArr,
                          int N, int Hh, int Cc) {
  int gid = blockIdx.x * blockDim.x + threadIdx.x;
  int wid = gid >> 6;
  int lane = gid & 63;
  if (wid >= N * Hh) return;
  int hh = wid % Hh;
  const f16x2* row = (const f16x2*)(h + (size_t)wid * Cc);
  float ss = 0.f, dd = 0.f;
  for (int c2 = lane; c2 < Cc / 2; c2 += 64) {
    f16x2 v = row[c2];
    float v0 = (float)v.x, v1 = (float)v.y;
    ss += v0 * a_src[hh * Cc + 2 * c2] + v1 * a_src[hh * Cc + 2 * c2 + 1];
    dd += v0 * a_dst[hh * Cc + 2 * c2] + v1 * a_dst[hh * Cc + 2 * c2 + 1];
  }
#pragma unroll
  for (int off = 32; off; off >>= 1) {
    ss += __shfl_down(ss, off);
    dd += __shfl_down(dd, off);
  }
  if (lane == 0) { sArr[wid] = ss; dArr[wid] = dd; }
}

// ---------------------------------------------------------------------------
// Per-destination segment softmax + aggregation (CSR, no atomics).
// Gather is wave-per-edge: each wave covers a full CT-col row with
// (CT/64)-wide f16 vector loads (16B/lane at CT=512); WAVES waves stripe
// across the edge list; cross-wave reduce through LDS at the end.
// ---------------------------------------------------------------------------
template <int HH, int CT, int WAVES, bool DOELU, typename OutT>
__global__ __launch_bounds__(WAVES * 64) void k_aggregate(
    const f16* __restrict__ hin, const float* __restrict__ sArr,
    const float* __restrict__ dArr, const int* __restrict__ row_ptr,
    const int* __restrict__ perm, const int* __restrict__ srcArr,
    const float* __restrict__ bias, OutT* __restrict__ outp, int N, int E) {
  constexpr int BLOCK = WAVES * 64;
  constexpr int VEC = CT / 64;          // f16 elems per lane in gather
  constexpr int CPER = CT / HH;         // cols per head
  constexpr int CPT = CT / BLOCK;       // cols per thread in epilogue
  using gvec = typename VecT<VEC>::T;

  __shared__ float mx_sh[HH];
  __shared__ float denom_sh[HH];
  __shared__ float wbuf[BLOCK * HH];
  __shared__ int sbuf[BLOCK];
  __shared__ float accbuf[WAVES * CT];

  int n = blockIdx.x;
  int t = threadIdx.x;
  int wave = t >> 6, lane = t & 63;
  int e0 = row_ptr[n], e1 = row_ptr[n + 1];
  int deg = e1 - e0;

  float dloc[HH];
#pragma unroll
  for (int h = 0; h < HH; ++h) dloc[h] = dArr[n * HH + h];

  // pass 1 (wave 0): per-head max of leaky-relu'd logits
  if (t < 64) {
    float mx[HH];
#pragma unroll
    for (int h = 0; h < HH; ++h) mx[h] = -3.0e38f;
    for (int i = t; i < deg; i += 64) {
      int eid = perm[e0 + i];
      int s = (eid < E) ? srcArr[eid] : (eid - E);
#pragma unroll
      for (int h = 0; h < HH; ++h) {
        float e = sArr[s * HH + h] + dloc[h];
        e = (e > 0.f) ? e : 0.2f * e;
        mx[h] = fmaxf(mx[h], e);
      }
    }
#pragma unroll
    for (int h = 0; h < HH; ++h) {
#pragma unroll
      for (int off = 32; off; off >>= 1) mx[h] = fmaxf(mx[h], __shfl_down(mx[h], off));
    }
    if (t == 0) {
#pragma unroll
      for (int h = 0; h < HH; ++h) { mx_sh[h] = mx[h]; denom_sh[h] = 0.f; }
    }
  }
  __syncthreads();

  const int lanehead = (lane * VEC) / CPER;  // head owning this lane's cols
  float acc[VEC];
#pragma unroll
  for (int k = 0; k < VEC; ++k) acc[k] = 0.f;

  for (int base = 0; base < deg; base += BLOCK) {
    int cn = min(BLOCK, deg - base);
    if (t < cn) {
      int eid = perm[e0 + base + t];
      int s = (eid < E) ? srcArr[eid] : (eid - E);
      sbuf[t] = s;
#pragma unroll
      for (int h = 0; h < HH; ++h) {
        float e = sArr[s * HH + h] + dloc[h];
        e = (e > 0.f) ? e : 0.2f * e;
        wbuf[t * HH + h] = __expf(e - mx_sh[h]);
      }
    }
    __syncthreads();
    if (t < HH) {
      float dsum = 0.f;
      for (int i = 0; i < cn; ++i) dsum += wbuf[i * HH + t];
      denom_sh[t] += dsum;
    }
    // wave-per-edge gather: 16B/lane (CT=512), full row per wave
    for (int i = wave; i < cn; i += WAVES) {
      int s = sbuf[i];
      float w = wbuf[i * HH + lanehead];
      gvec v = *(const gvec*)(hin + (size_t)s * CT + lane * VEC);
#pragma unroll
      for (int k = 0; k < VEC; ++k) acc[k] += w * (float)v[k];
    }
    __syncthreads();
  }

  // cross-wave reduction through LDS
#pragma unroll
  for (int k = 0; k < VEC; ++k) accbuf[wave * CT + lane * VEC + k] = acc[k];
  __syncthreads();

#pragma unroll
  for (int p = 0; p < CPT; ++p) {
    int c = t * CPT + p;
    float sum = 0.f;
#pragma unroll
    for (int w = 0; w < WAVES; ++w) sum += accbuf[w * CT + c];
    float dn = denom_sh[c / CPER] + 1e-16f;
    float v = sum / dn + bias[c];
    if (DOELU) v = (v > 0.f) ? v : expm1f(v);
    outp[(size_t)n * CT + c] = (OutT)v;
  }
}

// ---------------------------------------------------------------------------
// Allocation head: z = relu(emb @ Wh1^T + bh1); score = sigmoid(z @ Wh2^T + bh2)
// Persistent blocks; Wh1 staged in LDS once per block (stride 132 breaks the
// stride-128 b128 bank aliasing). One wave per node iteration.
// ---------------------------------------------------------------------------
__global__ __launch_bounds__(256) void k_head(
    const float* __restrict__ emb, const float* __restrict__ Wh1,
    const float* __restrict__ bh1, const float* __restrict__ Wh2,
    const float* __restrict__ bh2, float* __restrict__ scores, int N) {
  __shared__ float w1s[64 * 132];
  __shared__ float w2s[64];
  __shared__ float b1s[64];
  int t = threadIdx.x;
  for (int i = t; i < 64 * 32; i += 256) {
    int r = i >> 5, c4 = i & 31;
    float4 v = ((const float4*)Wh1)[i];
    *(float4*)&w1s[r * 132 + c4 * 4] = v;
  }
  if (t < 64) { w2s[t] = Wh2[t]; b1s[t] = bh1[t]; }
  __syncthreads();
  float b2v = bh2[0];
  int wave = t >> 6, lane = t & 63;
  int gw = blockIdx.x * 4 + wave;
  int nw = gridDim.x * 4;
  for (int n = gw; n < N; n += nw) {
    float2 xv = ((const float2*)(emb + (size_t)n * 128))[lane];
    float z = b1s[lane];
#pragma unroll
    for (int j = 0; j < 32; ++j) {
      float4 w = *(const float4*)&w1s[lane * 132 + 4 * j];
      float a0 = __shfl(xv.x, 2 * j);
      float a1 = __shfl(xv.y, 2 * j);
      float a2 = __shfl(xv.x, 2 * j + 1);
      float a3 = __shfl(xv.y, 2 * j + 1);
      z += w.x * a0 + w.y * a1 + w.z * a2 + w.w * a3;
    }
    z = fmaxf(z, 0.f);
    float v = z * w2s[lane];
#pragma unroll
    for (int off = 32; off; off >>= 1) v += __shfl_down(v, off);
    if (lane == 0) scores[n] = 1.f / (1.f + __expf(-(v + b2v)));
  }
}

// ---------------------------------------------------------------------------

extern "C" void kernel_launch(void* const* d_in, const int* in_sizes, int n_in,
                              void* d_out, int out_size, void* d_ws, size_t ws_size,
                              hipStream_t stream) {
  const float* x   = (const float*)d_in[0];
  const int*   ei  = (const int*)d_in[1];
  const float* W1  = (const float*)d_in[2];
  const float* as1 = (const float*)d_in[3];
  const float* ad1 = (const float*)d_in[4];
  const float* b1  = (const float*)d_in[5];
  const float* W2  = (const float*)d_in[6];
  const float* as2 = (const float*)d_in[7];
  const float* ad2 = (const float*)d_in[8];
  const float* b2  = (const float*)d_in[9];
  const float* W3  = (const float*)d_in[10];
  const float* as3 = (const float*)d_in[11];
  const float* ad3 = (const float*)d_in[12];
  const float* b3  = (const float*)d_in[13];
  const float* Wh1 = (const float*)d_in[14];
  const float* bh1 = (const float*)d_in[15];
  const float* Wh2 = (const float*)d_in[16];
  const float* bh2 = (const float*)d_in[17];
  float* out = (float*)d_out;

  const int F = 256, HC = 512, H = 4, C = 128;
  const int N = in_sizes[0] / F;
  const int E = in_sizes[1] / 2;
  const int Et = E + N;
  const int* srcArr = ei;
  const int* dstArr = ei + E;

  char* ws = (char*)d_ws;
  size_t off = 0;
  auto alloc = [&](size_t bytes) -> void* {
    void* p = ws + off;
    off += (bytes + 255) & ~(size_t)255;
    return p;
  };
  f16*   h16    = (f16*)alloc((size_t)N * HC * 2);
  f16*   hAgg   = (f16*)alloc((size_t)N * HC * 2);
  f16*   xh     = (f16*)alloc((size_t)N * F * 2);
  f16*   W1h    = (f16*)alloc((size_t)HC * F * 2);
  f16*   W2h    = (f16*)alloc((size_t)HC * HC * 2);
  f16*   W3h    = (f16*)alloc((size_t)C * HC * 2);
  int* row_ptr  = (int*)alloc((size_t)(N + 1) * 4);
  int* cnt      = (int*)alloc((size_t)N * 4);
  int* cursor   = (int*)alloc((size_t)N * 4);
  int* perm     = (int*)alloc((size_t)Et * 4);
  float* sArr   = (float*)alloc((size_t)N * H * 4);
  float* dArr   = (float*)alloc((size_t)N * H * 4);
  (void)ws_size; (void)n_in; (void)out_size;

  // ---- CSR build ----
  hipMemsetAsync(cnt, 0, (size_t)N * 4, stream);
  int eb = (Et + 255) / 256;
  k_count<<<eb, 256, 0, stream>>>(dstArr, cnt, E, Et);
  k_scan<<<1, 1024, 0, stream>>>(cnt, row_ptr, N);
  k_copy<<<(N + 255) / 256, 256, 0, stream>>>(row_ptr, cursor, N);
  k_fill<<<eb, 256, 0, stream>>>(dstArr, cursor, perm, E, Et);

  // ---- fp16 conversions ----
  auto cvt = [&](const float* src, f16* dst, size_t n) {
    int n4 = (int)(n / 4);
    k_f2h<<<(n4 + 255) / 256, 256, 0, stream>>>(src, dst, n4);
  };
  cvt(x, xh, (size_t)N * F);
  cvt(W1, W1h, (size_t)HC * F);
  cvt(W2, W2h, (size_t)HC * HC);
  cvt(W3, W3h, (size_t)C * HC);

  // ---- layer 1: F -> H*C, elu ----
  dim3 g1(HC / 128, (N + 127) / 128);
  k_hgemm_nt<<<g1, 256, 0, stream>>>(xh, W1h, h16, N, HC, F);
  int sdb = (N * H * 64 + 255) / 256;
  k_attn_sd<<<sdb, 256, 0, stream>>>(h16, as1, ad1, sArr, dArr, N, H, C);
  k_aggregate<4, 512, 4, true, f16><<<N, 256, 0, stream>>>(
      h16, sArr, dArr, row_ptr, perm, srcArr, b1, hAgg, N, E);

  // ---- layer 2: H*C -> H*C, elu ----
  k_hgemm_nt<<<g1, 256, 0, stream>>>(hAgg, W2h, h16, N, HC, HC);
  k_attn_sd<<<sdb, 256, 0, stream>>>(h16, as2, ad2, sArr, dArr, N, H, C);
  k_aggregate<4, 512, 4, true, f16><<<N, 256, 0, stream>>>(
      h16, sArr, dArr, row_ptr, perm, srcArr, b2, hAgg, N, E);

  // ---- layer 3: H*C -> C, single head, no concat/elu -> embeddings ----
  dim3 g3(C / 128, (N + 127) / 128);
  k_hgemm_nt<<<g3, 256, 0, stream>>>(hAgg, W3h, h16, N, C, HC);
  int sdb3 = (N * 64 + 255) / 256;
  k_attn_sd<<<sdb3, 256, 0, stream>>>(h16, as3, ad3, sArr, dArr, N, 1, C);
  k_aggregate<1, 128, 2, false, float><<<N, 128, 0, stream>>>(
      h16, sArr, dArr, row_ptr, perm, srcArr, b3, out, N, E);

  // ---- allocation head ----
  k_head<<<512, 256, 0, stream>>>(out, Wh1, bh1, Wh2, bh2, out + (size_t)N * C, N);
}

// Round 6
// 1059.048 us; speedup vs baseline: 1.0087x; 1.0087x over previous
//
#include <hip/hip_runtime.h>
#include <math.h>

typedef _Float16 f16;
typedef f16 f16x2 __attribute__((ext_vector_type(2)));
typedef f16 f16x8 __attribute__((ext_vector_type(8)));
typedef float f32x4 __attribute__((ext_vector_type(4)));

template <int V> struct VecT;
template <> struct VecT<2> { using T = f16 __attribute__((ext_vector_type(2))); };
template <> struct VecT<8> { using T = f16 __attribute__((ext_vector_type(8))); };

// ---------------------------------------------------------------------------
// CSR build: histogram of dst -> exclusive scan -> fill permutation
// Edge id space: [0, E) = real edges, [E, E+N) = self loops (src=dst=id-E)
// ---------------------------------------------------------------------------

__global__ void k_count(const int* __restrict__ dstArr, int* __restrict__ cnt,
                        int E, int Et) {
  int i = blockIdx.x * blockDim.x + threadIdx.x;
  if (i >= Et) return;
  int d = (i < E) ? dstArr[i] : (i - E);
  atomicAdd(&cnt[d], 1);
}

__global__ __launch_bounds__(1024) void k_scan(const int* __restrict__ cnt,
                                               int* __restrict__ row_ptr, int n) {
  __shared__ int part[1024];
  int t = threadIdx.x;
  int items = (n + 1023) / 1024;
  int base = t * items;
  int local[64];
  int s = 0;
  for (int j = 0; j < items; ++j) {
    int idx = base + j;
    int v = (idx < n) ? cnt[idx] : 0;
    local[j] = s;
    s += v;
  }
  part[t] = s;
  __syncthreads();
  for (int off = 1; off < 1024; off <<= 1) {
    int v = (t >= off) ? part[t - off] : 0;
    __syncthreads();
    part[t] += v;
    __syncthreads();
  }
  int excl = (t == 0) ? 0 : part[t - 1];
  for (int j = 0; j < items; ++j) {
    int idx = base + j;
    if (idx < n) row_ptr[idx] = excl + local[j];
  }
  if (t == 1023) row_ptr[n] = part[1023];
}

__global__ void k_copy(const int* __restrict__ src, int* __restrict__ dst, int n) {
  int i = blockIdx.x * blockDim.x + threadIdx.x;
  if (i < n) dst[i] = src[i];
}

__global__ void k_fill(const int* __restrict__ dstArr, int* __restrict__ cursor,
                       int* __restrict__ perm, int E, int Et) {
  int i = blockIdx.x * blockDim.x + threadIdx.x;
  if (i >= Et) return;
  int d = (i < E) ? dstArr[i] : (i - E);
  int pos = atomicAdd(&cursor[d], 1);
  perm[pos] = i;
}

// ---------------------------------------------------------------------------
// fp32 -> fp16 conversion (vectorized by 4; n must be multiple of 4)
// ---------------------------------------------------------------------------
__global__ void k_f2h(const float* __restrict__ in, f16* __restrict__ out, int n4) {
  int i = blockIdx.x * blockDim.x + threadIdx.x;
  if (i >= n4) return;
  float4 v = ((const float4*)in)[i];
  union { f16 h[4]; double d; } u;
  u.h[0] = (f16)v.x; u.h[1] = (f16)v.y; u.h[2] = (f16)v.z; u.h[3] = (f16)v.w;
  ((double*)out)[i] = u.d;
}

// ---------------------------------------------------------------------------
// HGEMM (fp16 MFMA, fp32 accumulate): C[M,Nn] = A[M,K] @ B[Nn,K]^T
// 128x128 tile, BK=32, 256 thr = 4 waves, wave = 64x64 quadrant (4x4 MFMAs).
// ---------------------------------------------------------------------------
#define LDSW 40
__global__ __launch_bounds__(256) void k_hgemm_nt(
    const f16* __restrict__ A, const f16* __restrict__ B,
    f16* __restrict__ C, int M, int Nn, int K) {
  __shared__ f16 As[128 * LDSW];
  __shared__ f16 Bs[128 * LDSW];
  int tid = threadIdx.x;
  int wave = tid >> 6, lane = tid & 63;
  int quad = lane >> 4, l16 = lane & 15;
  int m0 = blockIdx.y * 128, n0 = blockIdx.x * 128;
  int wm = (wave & 1) * 64, wn = (wave >> 1) * 64;

  int srow = tid >> 2;
  int scol = (tid & 3) * 8;
  int ar0 = m0 + srow;       if (ar0 >= M) ar0 = M - 1;
  int ar1 = m0 + srow + 64;  if (ar1 >= M) ar1 = M - 1;
  const f16* Ap0 = A + (size_t)ar0 * K + scol;
  const f16* Ap1 = A + (size_t)ar1 * K + scol;
  const f16* Bp0 = B + (size_t)(n0 + srow) * K + scol;
  const f16* Bp1 = B + (size_t)(n0 + srow + 64) * K + scol;
  f16* Asw0 = &As[srow * LDSW + scol];
  f16* Asw1 = &As[(srow + 64) * LDSW + scol];
  f16* Bsw0 = &Bs[srow * LDSW + scol];
  f16* Bsw1 = &Bs[(srow + 64) * LDSW + scol];

  const f16* Ard[4];
  const f16* Brd[4];
#pragma unroll
  for (int i = 0; i < 4; ++i) {
    Ard[i] = &As[(wm + i * 16 + l16) * LDSW + quad * 8];
    Brd[i] = &Bs[(wn + i * 16 + l16) * LDSW + quad * 8];
  }

  f32x4 acc[4][4];
#pragma unroll
  for (int i = 0; i < 4; ++i)
#pragma unroll
    for (int j = 0; j < 4; ++j) acc[i][j] = (f32x4)(0.f);

  for (int k0 = 0; k0 < K; k0 += 32) {
    f16x8 av0 = *(const f16x8*)(Ap0 + k0);
    f16x8 av1 = *(const f16x8*)(Ap1 + k0);
    f16x8 bv0 = *(const f16x8*)(Bp0 + k0);
    f16x8 bv1 = *(const f16x8*)(Bp1 + k0);
    __syncthreads();
    *(f16x8*)Asw0 = av0;
    *(f16x8*)Asw1 = av1;
    *(f16x8*)Bsw0 = bv0;
    *(f16x8*)Bsw1 = bv1;
    __syncthreads();
    f16x8 af[4], bf[4];
#pragma unroll
    for (int i = 0; i < 4; ++i) af[i] = *(const f16x8*)Ard[i];
#pragma unroll
    for (int j = 0; j < 4; ++j) bf[j] = *(const f16x8*)Brd[j];
#pragma unroll
    for (int i = 0; i < 4; ++i)
#pragma unroll
      for (int j = 0; j < 4; ++j)
        acc[i][j] = __builtin_amdgcn_mfma_f32_16x16x32_f16(af[i], bf[j], acc[i][j], 0, 0, 0);
  }

#pragma unroll
  for (int i = 0; i < 4; ++i) {
#pragma unroll
    for (int r = 0; r < 4; ++r) {
      int m = m0 + wm + i * 16 + quad * 4 + r;
      if (m < M) {
        f16* Cp = C + (size_t)m * Nn + n0 + wn + l16;
#pragma unroll
        for (int j = 0; j < 4; ++j) Cp[j * 16] = (f16)acc[i][j][r];
      }
    }
  }
}

// ---------------------------------------------------------------------------
// Per-node attention scalars from fp16 h: s[n,h] = <h[n,h,:], a_src[h,:]>.
// ---------------------------------------------------------------------------
__global__ void k_attn_sd(const f16* __restrict__ h,
                          const float* __restrict__ a_src,
                          const float* __restrict__ a_dst,
                          float* __restrict__ sArr, float* __restrict__ dArr,
                          int N, int Hh, int Cc) {
  int gid = blockIdx.x * blockDim.x + threadIdx.x;
  int wid = gid >> 6;
  int lane = gid & 63;
  if (wid >= N * Hh) return;
  int hh = wid % Hh;
  const f16x2* row = (const f16x2*)(h + (size_t)wid * Cc);
  float ss = 0.f, dd = 0.f;
  for (int c2 = lane; c2 < Cc / 2; c2 += 64) {
    f16x2 v = row[c2];
    float v0 = (float)v.x, v1 = (float)v.y;
    ss += v0 * a_src[hh * Cc + 2 * c2] + v1 * a_src[hh * Cc + 2 * c2 + 1];
    dd += v0 * a_dst[hh * Cc + 2 * c2] + v1 * a_dst[hh * Cc + 2 * c2 + 1];
  }
#pragma unroll
  for (int off = 32; off; off >>= 1) {
    ss += __shfl_down(ss, off);
    dd += __shfl_down(dd, off);
  }
  if (lane == 0) { sArr[wid] = ss; dArr[wid] = dd; }
}

// ---------------------------------------------------------------------------
// Global per-head max of sArr (two-stage, deterministic). Shift for softmax:
// leaky monotone => max_e leaky(s+d) = leaky(max_e s + d) <= leaky(gmax + d).
// ---------------------------------------------------------------------------
__global__ __launch_bounds__(256) void k_gmax_p(const float* __restrict__ s,
                                                float* __restrict__ part,
                                                int nrows, int HH) {
  __shared__ float red[4 * 4];
  float mx[4];
#pragma unroll
  for (int h = 0; h < 4; ++h) mx[h] = -3.0e38f;
  for (int r = blockIdx.x * 256 + threadIdx.x; r < nrows; r += gridDim.x * 256)
    for (int h = 0; h < HH; ++h) mx[h] = fmaxf(mx[h], s[r * HH + h]);
  for (int h = 0; h < HH; ++h)
#pragma unroll
    for (int off = 32; off; off >>= 1) mx[h] = fmaxf(mx[h], __shfl_down(mx[h], off));
  int wave = threadIdx.x >> 6, lane = threadIdx.x & 63;
  if (lane == 0)
    for (int h = 0; h < HH; ++h) red[wave * 4 + h] = mx[h];
  __syncthreads();
  if (threadIdx.x < HH) {
    float m = fmaxf(fmaxf(red[0 + threadIdx.x], red[4 + threadIdx.x]),
                    fmaxf(red[8 + threadIdx.x], red[12 + threadIdx.x]));
    part[blockIdx.x * HH + threadIdx.x] = m;
  }
}

__global__ void k_gmax_f(const float* __restrict__ part, float* __restrict__ gmax,
                         int P, int HH) {
  int h = threadIdx.x;
  if (h < HH) {
    float m = -3.0e38f;
    for (int i = 0; i < P; ++i) m = fmaxf(m, part[i * HH + h]);
    gmax[h] = m;
  }
}

// ---------------------------------------------------------------------------
// Segment softmax + aggregation: ONE WAVE PER NODE, no barriers, no LDS.
// Chunk of <=64 edges: lane-parallel perm/src/logit gather, then per-edge
// broadcast (shfl) + full-row gather (VEC f16/lane). Denominator accumulated
// wave-uniformly in registers. Shift = leaky(gmax + d_n) (>= segment max).
// ---------------------------------------------------------------------------
template <int HH, int CT, bool DOELU, typename OutT>
__global__ __launch_bounds__(256) void k_aggregate(
    const f16* __restrict__ hin, const float* __restrict__ sArr,
    const float* __restrict__ dArr, const int* __restrict__ row_ptr,
    const int* __restrict__ perm, const int* __restrict__ srcArr,
    const float* __restrict__ gmax, const float* __restrict__ bias,
    OutT* __restrict__ outp, int N, int E) {
  constexpr int VEC = CT / 64;          // f16 elems per lane (8 @CT=512)
  constexpr int CPER = CT / HH;         // cols per head
  using gvec = typename VecT<VEC>::T;

  int n = blockIdx.x * 4 + (threadIdx.x >> 6);
  int lane = threadIdx.x & 63;
  if (n >= N) return;
  int e0 = row_ptr[n];
  int deg = row_ptr[n + 1] - e0;

  float dloc[HH], mn[HH];
#pragma unroll
  for (int h = 0; h < HH; ++h) {
    dloc[h] = dArr[n * HH + h];
    float m = gmax[h] + dloc[h];
    mn[h] = (m > 0.f) ? m : 0.2f * m;
  }

  const int lanehead = (HH == 1) ? 0 : (lane * VEC) / CPER;
  float acc[VEC];
#pragma unroll
  for (int k = 0; k < VEC; ++k) acc[k] = 0.f;
  float denom[HH];
#pragma unroll
  for (int h = 0; h < HH; ++h) denom[h] = 0.f;

  for (int base = 0; base < deg; base += 64) {
    int cn = min(64, deg - base);
    int s_l = n;
    float w_l[HH];
#pragma unroll
    for (int h = 0; h < HH; ++h) w_l[h] = 0.f;
    if (lane < cn) {
      int eid = perm[e0 + base + lane];
      s_l = (eid < E) ? srcArr[eid] : (eid - E);
      if (HH == 4) {
        float4 sv = ((const float4*)sArr)[s_l];
        float svv[4] = {sv.x, sv.y, sv.z, sv.w};
#pragma unroll
        for (int h = 0; h < 4; ++h) {
          float e = svv[h] + dloc[h];
          e = (e > 0.f) ? e : 0.2f * e;
          w_l[h] = __expf(e - mn[h]);
        }
      } else {
        float e = sArr[s_l] + dloc[0];
        e = (e > 0.f) ? e : 0.2f * e;
        w_l[0] = __expf(e - mn[0]);
      }
    }
    for (int i = 0; i < cn; ++i) {
      int s = __shfl(s_l, i);
      float wh[HH];
#pragma unroll
      for (int h = 0; h < HH; ++h) {
        wh[h] = __shfl(w_l[h], i);
        denom[h] += wh[h];
      }
      float w = wh[lanehead];
      gvec v = *(const gvec*)(hin + (size_t)s * CT + lane * VEC);
#pragma unroll
      for (int k = 0; k < VEC; ++k) acc[k] += w * (float)v[k];
    }
  }

  float dn = denom[lanehead] + 1e-16f;
  struct alignas(sizeof(OutT) * VEC) OutV { OutT v[VEC]; } ov;
#pragma unroll
  for (int k = 0; k < VEC; ++k) {
    float v = acc[k] / dn + bias[lane * VEC + k];
    if (DOELU) v = (v > 0.f) ? v : expm1f(v);
    ov.v[k] = (OutT)v;
  }
  *(OutV*)(outp + (size_t)n * CT + lane * VEC) = ov;
}

// ---------------------------------------------------------------------------
// Allocation head (Wh1 staged in LDS, persistent blocks)
// ---------------------------------------------------------------------------
__global__ __launch_bounds__(256) void k_head(
    const float* __restrict__ emb, const float* __restrict__ Wh1,
    const float* __restrict__ bh1, const float* __restrict__ Wh2,
    const float* __restrict__ bh2, float* __restrict__ scores, int N) {
  __shared__ float w1s[64 * 132];
  __shared__ float w2s[64];
  __shared__ float b1s[64];
  int t = threadIdx.x;
  for (int i = t; i < 64 * 32; i += 256) {
    int r = i >> 5, c4 = i & 31;
    float4 v = ((const float4*)Wh1)[i];
    *(float4*)&w1s[r * 132 + c4 * 4] = v;
  }
  if (t < 64) { w2s[t] = Wh2[t]; b1s[t] = bh1[t]; }
  __syncthreads();
  float b2v = bh2[0];
  int wave = t >> 6, lane = t & 63;
  int gw = blockIdx.x * 4 + wave;
  int nw = gridDim.x * 4;
  for (int n = gw; n < N; n += nw) {
    float2 xv = ((const float2*)(emb + (size_t)n * 128))[lane];
    float z = b1s[lane];
#pragma unroll
    for (int j = 0; j < 32; ++j) {
      float4 w = *(const float4*)&w1s[lane * 132 + 4 * j];
      float a0 = __shfl(xv.x, 2 * j);
      float a1 = __shfl(xv.y, 2 * j);
      float a2 = __shfl(xv.x, 2 * j + 1);
      float a3 = __shfl(xv.y, 2 * j + 1);
      z += w.x * a0 + w.y * a1 + w.z * a2 + w.w * a3;
    }
    z = fmaxf(z, 0.f);
    float v = z * w2s[lane];
#pragma unroll
    for (int off = 32; off; off >>= 1) v += __shfl_down(v, off);
    if (lane == 0) scores[n] = 1.f / (1.f + __expf(-(v + b2v)));
  }
}

// ---------------------------------------------------------------------------

extern "C" void kernel_launch(void* const* d_in, const int* in_sizes, int n_in,
                              void* d_out, int out_size, void* d_ws, size_t ws_size,
                              hipStream_t stream) {
  const float* x   = (const float*)d_in[0];
  const int*   ei  = (const int*)d_in[1];
  const float* W1  = (const float*)d_in[2];
  const float* as1 = (const float*)d_in[3];
  const float* ad1 = (const float*)d_in[4];
  const float* b1  = (const float*)d_in[5];
  const float* W2  = (const float*)d_in[6];
  const float* as2 = (const float*)d_in[7];
  const float* ad2 = (const float*)d_in[8];
  const float* b2  = (const float*)d_in[9];
  const float* W3  = (const float*)d_in[10];
  const float* as3 = (const float*)d_in[11];
  const float* ad3 = (const float*)d_in[12];
  const float* b3  = (const float*)d_in[13];
  const float* Wh1 = (const float*)d_in[14];
  const float* bh1 = (const float*)d_in[15];
  const float* Wh2 = (const float*)d_in[16];
  const float* bh2 = (const float*)d_in[17];
  float* out = (float*)d_out;

  const int F = 256, HC = 512, H = 4, C = 128;
  const int N = in_sizes[0] / F;
  const int E = in_sizes[1] / 2;
  const int Et = E + N;
  const int* srcArr = ei;
  const int* dstArr = ei + E;

  char* ws = (char*)d_ws;
  size_t off = 0;
  auto alloc = [&](size_t bytes) -> void* {
    void* p = ws + off;
    off += (bytes + 255) & ~(size_t)255;
    return p;
  };
  f16*   h16    = (f16*)alloc((size_t)N * HC * 2);
  f16*   hAgg   = (f16*)alloc((size_t)N * HC * 2);
  f16*   xh     = (f16*)alloc((size_t)N * F * 2);
  f16*   W1h    = (f16*)alloc((size_t)HC * F * 2);
  f16*   W2h    = (f16*)alloc((size_t)HC * HC * 2);
  f16*   W3h    = (f16*)alloc((size_t)C * HC * 2);
  int* row_ptr  = (int*)alloc((size_t)(N + 1) * 4);
  int* cnt      = (int*)alloc((size_t)N * 4);
  int* cursor   = (int*)alloc((size_t)N * 4);
  int* perm     = (int*)alloc((size_t)Et * 4);
  float* sArr   = (float*)alloc((size_t)N * H * 4);
  float* dArr   = (float*)alloc((size_t)N * H * 4);
  float* gpart  = (float*)alloc((size_t)64 * 4 * 4);
  float* gmaxb  = (float*)alloc((size_t)4 * 4);
  (void)ws_size; (void)n_in; (void)out_size;

  // ---- CSR build ----
  hipMemsetAsync(cnt, 0, (size_t)N * 4, stream);
  int eb = (Et + 255) / 256;
  k_count<<<eb, 256, 0, stream>>>(dstArr, cnt, E, Et);
  k_scan<<<1, 1024, 0, stream>>>(cnt, row_ptr, N);
  k_copy<<<(N + 255) / 256, 256, 0, stream>>>(row_ptr, cursor, N);
  k_fill<<<eb, 256, 0, stream>>>(dstArr, cursor, perm, E, Et);

  // ---- fp16 conversions ----
  auto cvt = [&](const float* src, f16* dst, size_t n) {
    int n4 = (int)(n / 4);
    k_f2h<<<(n4 + 255) / 256, 256, 0, stream>>>(src, dst, n4);
  };
  cvt(x, xh, (size_t)N * F);
  cvt(W1, W1h, (size_t)HC * F);
  cvt(W2, W2h, (size_t)HC * HC);
  cvt(W3, W3h, (size_t)C * HC);

  int aggGrid = (N + 3) / 4;

  // ---- layer 1: F -> H*C, elu ----
  dim3 g1(HC / 128, (N + 127) / 128);
  k_hgemm_nt<<<g1, 256, 0, stream>>>(xh, W1h, h16, N, HC, F);
  int sdb = (N * H * 64 + 255) / 256;
  k_attn_sd<<<sdb, 256, 0, stream>>>(h16, as1, ad1, sArr, dArr, N, H, C);
  k_gmax_p<<<64, 256, 0, stream>>>(sArr, gpart, N, H);
  k_gmax_f<<<1, 64, 0, stream>>>(gpart, gmaxb, 64, H);
  k_aggregate<4, 512, true, f16><<<aggGrid, 256, 0, stream>>>(
      h16, sArr, dArr, row_ptr, perm, srcArr, gmaxb, b1, hAgg, N, E);

  // ---- layer 2: H*C -> H*C, elu ----
  k_hgemm_nt<<<g1, 256, 0, stream>>>(hAgg, W2h, h16, N, HC, HC);
  k_attn_sd<<<sdb, 256, 0, stream>>>(h16, as2, ad2, sArr, dArr, N, H, C);
  k_gmax_p<<<64, 256, 0, stream>>>(sArr, gpart, N, H);
  k_gmax_f<<<1, 64, 0, stream>>>(gpart, gmaxb, 64, H);
  k_aggregate<4, 512, true, f16><<<aggGrid, 256, 0, stream>>>(
      h16, sArr, dArr, row_ptr, perm, srcArr, gmaxb, b2, hAgg, N, E);

  // ---- layer 3: H*C -> C, single head, no concat/elu -> embeddings ----
  dim3 g3(C / 128, (N + 127) / 128);
  k_hgemm_nt<<<g3, 256, 0, stream>>>(hAgg, W3h, h16, N, C, HC);
  int sdb3 = (N * 64 + 255) / 256;
  k_attn_sd<<<sdb3, 256, 0, stream>>>(h16, as3, ad3, sArr, dArr, N, 1, C);
  k_gmax_p<<<64, 256, 0, stream>>>(sArr, gpart, N, 1);
  k_gmax_f<<<1, 64, 0, stream>>>(gpart, gmaxb, 64, 1);
  k_aggregate<1, 128, false, float><<<aggGrid, 256, 0, stream>>>(
      h16, sArr, dArr, row_ptr, perm, srcArr, gmaxb, b3, out, N, E);

  // ---- allocation head ----
  k_head<<<512, 256, 0, stream>>>(out, Wh1, bh1, Wh2, bh2, out + (size_t)N * C, N);
}

// Round 7
// 997.882 us; speedup vs baseline: 1.0706x; 1.0613x over previous
//
#include <hip/hip_runtime.h>
#include <math.h>

typedef _Float16 f16;
typedef f16 f16x2 __attribute__((ext_vector_type(2)));
typedef f16 f16x8 __attribute__((ext_vector_type(8)));
typedef float f32x4 __attribute__((ext_vector_type(4)));

template <int V> struct VecT;
template <> struct VecT<2> { using T = f16 __attribute__((ext_vector_type(2))); };
template <> struct VecT<8> { using T = f16 __attribute__((ext_vector_type(8))); };

__device__ __forceinline__ unsigned ordf(float f) {
  unsigned u = __float_as_uint(f);
  return (u >> 31) ? ~u : (u | 0x80000000u);
}
__device__ __forceinline__ float unordf(unsigned u) {
  return (u >> 31) ? __uint_as_float(u & 0x7fffffffu) : __uint_as_float(~u);
}

// ---------------------------------------------------------------------------
// CSR build: histogram of dst -> exclusive scan -> fill permutation
// Edge id space: [0, E) = real edges, [E, E+N) = self loops (src=dst=id-E)
// ---------------------------------------------------------------------------

__global__ void k_count(const int* __restrict__ dstArr, int* __restrict__ cnt,
                        int E, int Et) {
  int i = blockIdx.x * blockDim.x + threadIdx.x;
  if (i >= Et) return;
  int d = (i < E) ? dstArr[i] : (i - E);
  atomicAdd(&cnt[d], 1);
}

__global__ __launch_bounds__(1024) void k_scan(const int* __restrict__ cnt,
                                               int* __restrict__ row_ptr,
                                               int* __restrict__ cursor, int n) {
  __shared__ int part[1024];
  int t = threadIdx.x;
  int items = (n + 1023) / 1024;
  int base = t * items;
  int local[64];
  int s = 0;
  for (int j = 0; j < items; ++j) {
    int idx = base + j;
    int v = (idx < n) ? cnt[idx] : 0;
    local[j] = s;
    s += v;
  }
  part[t] = s;
  __syncthreads();
  for (int off = 1; off < 1024; off <<= 1) {
    int v = (t >= off) ? part[t - off] : 0;
    __syncthreads();
    part[t] += v;
    __syncthreads();
  }
  int excl = (t == 0) ? 0 : part[t - 1];
  for (int j = 0; j < items; ++j) {
    int idx = base + j;
    if (idx < n) { int v = excl + local[j]; row_ptr[idx] = v; cursor[idx] = v; }
  }
  if (t == 1023) row_ptr[n] = part[1023];
}

__global__ void k_fill(const int* __restrict__ dstArr, int* __restrict__ cursor,
                       int* __restrict__ perm, int E, int Et) {
  int i = blockIdx.x * blockDim.x + threadIdx.x;
  if (i >= Et) return;
  int d = (i < E) ? dstArr[i] : (i - E);
  int pos = atomicAdd(&cursor[d], 1);
  perm[pos] = i;
}

// ---------------------------------------------------------------------------
// fp32 -> fp16 conversion, 4 segments in one launch (each n multiple of 4)
// ---------------------------------------------------------------------------
__global__ void k_f2h4(const float* s0, f16* d0, int n0,
                       const float* s1, f16* d1, int n1,
                       const float* s2, f16* d2, int n2,
                       const float* s3, f16* d3, int n3) {
  int i = blockIdx.x * blockDim.x + threadIdx.x;
  const float* s; f16* d;
  if (i < n0) { s = s0; d = d0; }
  else if ((i -= n0) < n1) { s = s1; d = d1; }
  else if ((i -= n1) < n2) { s = s2; d = d2; }
  else if ((i -= n2) < n3) { s = s3; d = d3; }
  else return;
  float4 v = ((const float4*)s)[i];
  union { f16 h[4]; double dd; } u;
  u.h[0] = (f16)v.x; u.h[1] = (f16)v.y; u.h[2] = (f16)v.z; u.h[3] = (f16)v.w;
  ((double*)d)[i] = u.dd;
}

// ---------------------------------------------------------------------------
// HGEMM (fp16 MFMA, fp32 accumulate): C[M,Nn] = A[M,K] @ B[Nn,K]^T
// 128x128 tile, BK=32, 256 thr = 4 waves, wave = 64x64 quadrant (4x4 MFMAs).
// Fused GAT-attention epilogue: this block covers exactly one head's 128
// cols, so it computes s[n,head] = <h row, a_src[head]>, d likewise, from the
// fp32 accumulators (butterfly over the 16 col-lanes + LDS combine of the two
// wn halves), and atomicMax's the order-uint global max of s.
// ---------------------------------------------------------------------------
#define LDSW 40
__global__ __launch_bounds__(256) void k_hgemm_nt(
    const f16* __restrict__ A, const f16* __restrict__ B,
    f16* __restrict__ C, int M, int Nn, int K,
    const float* __restrict__ a_src, const float* __restrict__ a_dst,
    float* __restrict__ sArr, float* __restrict__ dArr,
    unsigned* __restrict__ gmaxU, int H) {
  __shared__ f16 As[128 * LDSW];
  __shared__ f16 Bs[128 * LDSW];
  int tid = threadIdx.x;
  int wave = tid >> 6, lane = tid & 63;
  int quad = lane >> 4, l16 = lane & 15;
  int m0 = blockIdx.y * 128, n0 = blockIdx.x * 128;
  int wm = (wave & 1) * 64, wn = (wave >> 1) * 64;

  int srow = tid >> 2;
  int scol = (tid & 3) * 8;
  int ar0 = m0 + srow;       if (ar0 >= M) ar0 = M - 1;
  int ar1 = m0 + srow + 64;  if (ar1 >= M) ar1 = M - 1;
  const f16* Ap0 = A + (size_t)ar0 * K + scol;
  const f16* Ap1 = A + (size_t)ar1 * K + scol;
  const f16* Bp0 = B + (size_t)(n0 + srow) * K + scol;
  const f16* Bp1 = B + (size_t)(n0 + srow + 64) * K + scol;
  f16* Asw0 = &As[srow * LDSW + scol];
  f16* Asw1 = &As[(srow + 64) * LDSW + scol];
  f16* Bsw0 = &Bs[srow * LDSW + scol];
  f16* Bsw1 = &Bs[(srow + 64) * LDSW + scol];

  const f16* Ard[4];
  const f16* Brd[4];
#pragma unroll
  for (int i = 0; i < 4; ++i) {
    Ard[i] = &As[(wm + i * 16 + l16) * LDSW + quad * 8];
    Brd[i] = &Bs[(wn + i * 16 + l16) * LDSW + quad * 8];
  }

  f32x4 acc[4][4];
#pragma unroll
  for (int i = 0; i < 4; ++i)
#pragma unroll
    for (int j = 0; j < 4; ++j) acc[i][j] = (f32x4)(0.f);

  for (int k0 = 0; k0 < K; k0 += 32) {
    f16x8 av0 = *(const f16x8*)(Ap0 + k0);
    f16x8 av1 = *(const f16x8*)(Ap1 + k0);
    f16x8 bv0 = *(const f16x8*)(Bp0 + k0);
    f16x8 bv1 = *(const f16x8*)(Bp1 + k0);
    __syncthreads();
    *(f16x8*)Asw0 = av0;
    *(f16x8*)Asw1 = av1;
    *(f16x8*)Bsw0 = bv0;
    *(f16x8*)Bsw1 = bv1;
    __syncthreads();
    f16x8 af[4], bf[4];
#pragma unroll
    for (int i = 0; i < 4; ++i) af[i] = *(const f16x8*)Ard[i];
#pragma unroll
    for (int j = 0; j < 4; ++j) bf[j] = *(const f16x8*)Brd[j];
#pragma unroll
    for (int i = 0; i < 4; ++i)
#pragma unroll
      for (int j = 0; j < 4; ++j)
        acc[i][j] = __builtin_amdgcn_mfma_f32_16x16x32_f16(af[i], bf[j], acc[i][j], 0, 0, 0);
  }

  // ---- C store ----
#pragma unroll
  for (int i = 0; i < 4; ++i) {
#pragma unroll
    for (int r = 0; r < 4; ++r) {
      int m = m0 + wm + i * 16 + quad * 4 + r;
      if (m < M) {
        f16* Cp = C + (size_t)m * Nn + n0 + wn + l16;
#pragma unroll
        for (int j = 0; j < 4; ++j) Cp[j * 16] = (f16)acc[i][j][r];
      }
    }
  }

  // ---- fused attention scalars ----
  float av[4], ad[4];
#pragma unroll
  for (int j = 0; j < 4; ++j) {
    int col = n0 + wn + l16 + j * 16;
    av[j] = a_src[col];
    ad[j] = a_dst[col];
  }
  float sp[16], dp[16];
#pragma unroll
  for (int i = 0; i < 4; ++i)
#pragma unroll
    for (int r = 0; r < 4; ++r) {
      float ss = 0.f, dd = 0.f;
#pragma unroll
      for (int j = 0; j < 4; ++j) {
        ss += acc[i][j][r] * av[j];
        dd += acc[i][j][r] * ad[j];
      }
      // butterfly over the 16 col-lanes (masks stay within the group)
#pragma unroll
      for (int msk = 1; msk < 16; msk <<= 1) {
        ss += __shfl_xor(ss, msk);
        dd += __shfl_xor(dd, msk);
      }
      sp[i * 4 + r] = ss;
      dp[i * 4 + r] = dd;
    }

  __syncthreads();  // done reading As/Bs; reuse as float scratch
  float* fb = (float*)As;   // fb[0..255]: s halves; fb[256..511]: d halves
  int wv = wn >> 6;
  if (l16 == 0) {
#pragma unroll
    for (int i = 0; i < 4; ++i)
#pragma unroll
      for (int r = 0; r < 4; ++r) {
        int row = wm + i * 16 + quad * 4 + r;
        fb[wv * 128 + row] = sp[i * 4 + r];
        fb[256 + wv * 128 + row] = dp[i * 4 + r];
      }
  }
  __syncthreads();
  if (tid < 128) {
    int m = m0 + tid;
    if (m < M) {
      float s = fb[tid] + fb[128 + tid];
      float d = fb[256 + tid] + fb[384 + tid];
      int head = n0 >> 7;
      sArr[(size_t)m * H + head] = s;
      dArr[(size_t)m * H + head] = d;
      atomicMax(&gmaxU[head], ordf(s));
    }
  }
}

// ---------------------------------------------------------------------------
// Segment softmax + aggregation: ONE WAVE PER NODE, no barriers, no LDS.
// Shift = leaky(gmax + d_n) >= segment max (leaky monotone; softmax
// shift-invariant). gmax passed as order-preserving uint.
// ---------------------------------------------------------------------------
template <int HH, int CT, bool DOELU, typename OutT>
__global__ __launch_bounds__(256) void k_aggregate(
    const f16* __restrict__ hin, const float* __restrict__ sArr,
    const float* __restrict__ dArr, const int* __restrict__ row_ptr,
    const int* __restrict__ perm, const int* __restrict__ srcArr,
    const unsigned* __restrict__ gmaxU, const float* __restrict__ bias,
    OutT* __restrict__ outp, int N, int E) {
  constexpr int VEC = CT / 64;          // f16 elems per lane (8 @CT=512)
  constexpr int CPER = CT / HH;         // cols per head
  using gvec = typename VecT<VEC>::T;

  int n = blockIdx.x * 4 + (threadIdx.x >> 6);
  int lane = threadIdx.x & 63;
  if (n >= N) return;
  int e0 = row_ptr[n];
  int deg = row_ptr[n + 1] - e0;

  float dloc[HH], mn[HH];
#pragma unroll
  for (int h = 0; h < HH; ++h) {
    dloc[h] = dArr[n * HH + h];
    float m = unordf(gmaxU[h]) + dloc[h];
    mn[h] = (m > 0.f) ? m : 0.2f * m;
  }

  const int lanehead = (HH == 1) ? 0 : (lane * VEC) / CPER;
  float acc[VEC];
#pragma unroll
  for (int k = 0; k < VEC; ++k) acc[k] = 0.f;
  float denom[HH];
#pragma unroll
  for (int h = 0; h < HH; ++h) denom[h] = 0.f;

  for (int base = 0; base < deg; base += 64) {
    int cn = min(64, deg - base);
    int s_l = n;
    float w_l[HH];
#pragma unroll
    for (int h = 0; h < HH; ++h) w_l[h] = 0.f;
    if (lane < cn) {
      int eid = perm[e0 + base + lane];
      s_l = (eid < E) ? srcArr[eid] : (eid - E);
      if (HH == 4) {
        float4 sv = ((const float4*)sArr)[s_l];
        float svv[4] = {sv.x, sv.y, sv.z, sv.w};
#pragma unroll
        for (int h = 0; h < 4; ++h) {
          float e = svv[h] + dloc[h];
          e = (e > 0.f) ? e : 0.2f * e;
          w_l[h] = __expf(e - mn[h]);
        }
      } else {
        float e = sArr[s_l] + dloc[0];
        e = (e > 0.f) ? e : 0.2f * e;
        w_l[0] = __expf(e - mn[0]);
      }
    }
    for (int i = 0; i < cn; ++i) {
      int s = __shfl(s_l, i);
      float wh[HH];
#pragma unroll
      for (int h = 0; h < HH; ++h) {
        wh[h] = __shfl(w_l[h], i);
        denom[h] += wh[h];
      }
      float w = wh[lanehead];
      gvec v = *(const gvec*)(hin + (size_t)s * CT + lane * VEC);
#pragma unroll
      for (int k = 0; k < VEC; ++k) acc[k] += w * (float)v[k];
    }
  }

  float dn = denom[lanehead] + 1e-16f;
  struct alignas(sizeof(OutT) * VEC) OutV { OutT v[VEC]; } ov;
#pragma unroll
  for (int k = 0; k < VEC; ++k) {
    float v = acc[k] / dn + bias[lane * VEC + k];
    if (DOELU) v = (v > 0.f) ? v : expm1f(v);
    ov.v[k] = (OutT)v;
  }
  *(OutV*)(outp + (size_t)n * CT + lane * VEC) = ov;
}

// ---------------------------------------------------------------------------
// Allocation head (Wh1 staged in LDS, persistent blocks)
// ---------------------------------------------------------------------------
__global__ __launch_bounds__(256) void k_head(
    const float* __restrict__ emb, const float* __restrict__ Wh1,
    const float* __restrict__ bh1, const float* __restrict__ Wh2,
    const float* __restrict__ bh2, float* __restrict__ scores, int N) {
  __shared__ float w1s[64 * 132];
  __shared__ float w2s[64];
  __shared__ float b1s[64];
  int t = threadIdx.x;
  for (int i = t; i < 64 * 32; i += 256) {
    int r = i >> 5, c4 = i & 31;
    float4 v = ((const float4*)Wh1)[i];
    *(float4*)&w1s[r * 132 + c4 * 4] = v;
  }
  if (t < 64) { w2s[t] = Wh2[t]; b1s[t] = bh1[t]; }
  __syncthreads();
  float b2v = bh2[0];
  int wave = t >> 6, lane = t & 63;
  int gw = blockIdx.x * 4 + wave;
  int nw = gridDim.x * 4;
  for (int n = gw; n < N; n += nw) {
    float2 xv = ((const float2*)(emb + (size_t)n * 128))[lane];
    float z = b1s[lane];
#pragma unroll
    for (int j = 0; j < 32; ++j) {
      float4 w = *(const float4*)&w1s[lane * 132 + 4 * j];
      float a0 = __shfl(xv.x, 2 * j);
      float a1 = __shfl(xv.y, 2 * j);
      float a2 = __shfl(xv.x, 2 * j + 1);
      float a3 = __shfl(xv.y, 2 * j + 1);
      z += w.x * a0 + w.y * a1 + w.z * a2 + w.w * a3;
    }
    z = fmaxf(z, 0.f);
    float v = z * w2s[lane];
#pragma unroll
    for (int off = 32; off; off >>= 1) v += __shfl_down(v, off);
    if (lane == 0) scores[n] = 1.f / (1.f + __expf(-(v + b2v)));
  }
}

// ---------------------------------------------------------------------------

extern "C" void kernel_launch(void* const* d_in, const int* in_sizes, int n_in,
                              void* d_out, int out_size, void* d_ws, size_t ws_size,
                              hipStream_t stream) {
  const float* x   = (const float*)d_in[0];
  const int*   ei  = (const int*)d_in[1];
  const float* W1  = (const float*)d_in[2];
  const float* as1 = (const float*)d_in[3];
  const float* ad1 = (const float*)d_in[4];
  const float* b1  = (const float*)d_in[5];
  const float* W2  = (const float*)d_in[6];
  const float* as2 = (const float*)d_in[7];
  const float* ad2 = (const float*)d_in[8];
  const float* b2  = (const float*)d_in[9];
  const float* W3  = (const float*)d_in[10];
  const float* as3 = (const float*)d_in[11];
  const float* ad3 = (const float*)d_in[12];
  const float* b3  = (const float*)d_in[13];
  const float* Wh1 = (const float*)d_in[14];
  const float* bh1 = (const float*)d_in[15];
  const float* Wh2 = (const float*)d_in[16];
  const float* bh2 = (const float*)d_in[17];
  float* out = (float*)d_out;

  const int F = 256, HC = 512, H = 4, C = 128;
  const int N = in_sizes[0] / F;
  const int E = in_sizes[1] / 2;
  const int Et = E + N;
  const int* srcArr = ei;
  const int* dstArr = ei + E;

  char* ws = (char*)d_ws;
  size_t off = 0;
  auto alloc = [&](size_t bytes) -> void* {
    void* p = ws + off;
    off += (bytes + 255) & ~(size_t)255;
    return p;
  };
  f16*   h16    = (f16*)alloc((size_t)N * HC * 2);
  f16*   hAgg   = (f16*)alloc((size_t)N * HC * 2);
  f16*   xh     = (f16*)alloc((size_t)N * F * 2);
  f16*   W1h    = (f16*)alloc((size_t)HC * F * 2);
  f16*   W2h    = (f16*)alloc((size_t)HC * HC * 2);
  f16*   W3h    = (f16*)alloc((size_t)C * HC * 2);
  int* row_ptr  = (int*)alloc((size_t)(N + 1) * 4);
  // zero region: cnt (N ints) + 3x4 gmax uints, one memset
  char* zr      = (char*)alloc((size_t)N * 4 + 64);
  int* cnt      = (int*)zr;
  unsigned* gm1 = (unsigned*)(zr + (size_t)N * 4);
  unsigned* gm2 = gm1 + 4;
  unsigned* gm3 = gm1 + 8;
  int* cursor   = (int*)alloc((size_t)N * 4);
  int* perm     = (int*)alloc((size_t)Et * 4);
  float* sArr   = (float*)alloc((size_t)N * H * 4);
  float* dArr   = (float*)alloc((size_t)N * H * 4);
  (void)ws_size; (void)n_in; (void)out_size;

  // ---- CSR build ----
  hipMemsetAsync(zr, 0, (size_t)N * 4 + 64, stream);
  int eb = (Et + 255) / 256;
  k_count<<<eb, 256, 0, stream>>>(dstArr, cnt, E, Et);
  k_scan<<<1, 1024, 0, stream>>>(cnt, row_ptr, cursor, N);
  k_fill<<<eb, 256, 0, stream>>>(dstArr, cursor, perm, E, Et);

  // ---- fp16 conversions (one launch) ----
  int c0 = N * F / 4, c1 = HC * F / 4, c2 = HC * HC / 4, c3 = C * HC / 4;
  int ctot = c0 + c1 + c2 + c3;
  k_f2h4<<<(ctot + 255) / 256, 256, 0, stream>>>(x, xh, c0, W1, W1h, c1,
                                                 W2, W2h, c2, W3, W3h, c3);

  int aggGrid = (N + 3) / 4;
  dim3 g1(HC / 128, (N + 127) / 128);
  dim3 g3(C / 128, (N + 127) / 128);

  // ---- layer 1: F -> H*C, elu ----
  k_hgemm_nt<<<g1, 256, 0, stream>>>(xh, W1h, h16, N, HC, F,
                                     as1, ad1, sArr, dArr, gm1, H);
  k_aggregate<4, 512, true, f16><<<aggGrid, 256, 0, stream>>>(
      h16, sArr, dArr, row_ptr, perm, srcArr, gm1, b1, hAgg, N, E);

  // ---- layer 2: H*C -> H*C, elu ----
  k_hgemm_nt<<<g1, 256, 0, stream>>>(hAgg, W2h, h16, N, HC, HC,
                                     as2, ad2, sArr, dArr, gm2, H);
  k_aggregate<4, 512, true, f16><<<aggGrid, 256, 0, stream>>>(
      h16, sArr, dArr, row_ptr, perm, srcArr, gm2, b2, hAgg, N, E);

  // ---- layer 3: H*C -> C, single head, no concat/elu -> embeddings ----
  k_hgemm_nt<<<g3, 256, 0, stream>>>(hAgg, W3h, h16, N, C, HC,
                                     as3, ad3, sArr, dArr, gm3, 1);
  k_aggregate<1, 128, false, float><<<aggGrid, 256, 0, stream>>>(
      h16, sArr, dArr, row_ptr, perm, srcArr, gm3, b3, out, N, E);

  // ---- allocation head ----
  k_head<<<512, 256, 0, stream>>>(out, Wh1, bh1, Wh2, bh2, out + (size_t)N * C, N);
}

// Round 8
// 861.545 us; speedup vs baseline: 1.2400x; 1.1582x over previous
//
#include <hip/hip_runtime.h>
#include <math.h>

typedef _Float16 f16;
typedef f16 f16x2 __attribute__((ext_vector_type(2)));
typedef f16 f16x8 __attribute__((ext_vector_type(8)));
typedef float f32x4 __attribute__((ext_vector_type(4)));

template <int V> struct VecT;
template <> struct VecT<2> { using T = f16 __attribute__((ext_vector_type(2))); };
template <> struct VecT<8> { using T = f16 __attribute__((ext_vector_type(8))); };

__device__ __forceinline__ unsigned ordf(float f) {
  unsigned u = __float_as_uint(f);
  return (u >> 31) ? ~u : (u | 0x80000000u);
}
__device__ __forceinline__ float unordf(unsigned u) {
  return (u >> 31) ? __uint_as_float(u & 0x7fffffffu) : __uint_as_float(~u);
}

// ---------------------------------------------------------------------------
// CSR build: histogram of dst -> 3-stage parallel scan -> fill permutation
// Edge id space: [0, E) = real edges, [E, E+N) = self loops (src=dst=id-E)
// ---------------------------------------------------------------------------

__global__ void k_count(const int* __restrict__ dstArr, int* __restrict__ cnt,
                        int E, int Et) {
  int i = blockIdx.x * blockDim.x + threadIdx.x;
  if (i >= Et) return;
  int d = (i < E) ? dstArr[i] : (i - E);
  atomicAdd(&cnt[d], 1);
}

// stage A: 1024 elems per block (256 thr x int4), local exclusive prefixes
// into row_ptr, block total into bsum[b].
__global__ __launch_bounds__(256) void k_scanA(const int* __restrict__ cnt,
                                               int* __restrict__ row_ptr,
                                               int* __restrict__ bsum, int n) {
  __shared__ int part[256];
  int t = threadIdx.x;
  int base = blockIdx.x * 1024 + t * 4;
  int4 v = make_int4(0, 0, 0, 0);
  if (base + 3 < n) v = *(const int4*)&cnt[base];
  else {
    if (base + 0 < n) v.x = cnt[base + 0];
    if (base + 1 < n) v.y = cnt[base + 1];
    if (base + 2 < n) v.z = cnt[base + 2];
    if (base + 3 < n) v.w = cnt[base + 3];
  }
  int s = v.x + v.y + v.z + v.w;
  part[t] = s;
  __syncthreads();
  for (int off = 1; off < 256; off <<= 1) {
    int x = (t >= off) ? part[t - off] : 0;
    __syncthreads();
    part[t] += x;
    __syncthreads();
  }
  int p0 = (t == 0) ? 0 : part[t - 1];
  int p1 = p0 + v.x, p2 = p1 + v.y, p3 = p2 + v.z;
  if (base + 0 < n) row_ptr[base + 0] = p0;
  if (base + 1 < n) row_ptr[base + 1] = p1;
  if (base + 2 < n) row_ptr[base + 2] = p2;
  if (base + 3 < n) row_ptr[base + 3] = p3;
  if (t == 255) bsum[blockIdx.x] = part[255];
}

// stage B: single block scans bsum[0..nb) -> exclusive offsets; total at bsum[nb].
__global__ __launch_bounds__(1024) void k_scanB(int* __restrict__ bsum, int nb) {
  __shared__ int part[1024];
  int t = threadIdx.x;
  int v = (t < nb) ? bsum[t] : 0;
  part[t] = v;
  __syncthreads();
  for (int off = 1; off < 1024; off <<= 1) {
    int x = (t >= off) ? part[t - off] : 0;
    __syncthreads();
    part[t] += x;
    __syncthreads();
  }
  if (t < nb) bsum[t] = (t == 0) ? 0 : part[t - 1];
  if (t == 1023) bsum[nb] = part[1023];
}

// stage C: add block offsets in place; mirror to cursor; row_ptr[n] = total.
__global__ void k_scanC(int* __restrict__ row_ptr, int* __restrict__ cursor,
                        const int* __restrict__ bsum, int n, int nb) {
  int i = blockIdx.x * blockDim.x + threadIdx.x;
  if (i < n) {
    int v = row_ptr[i] + bsum[i >> 10];
    row_ptr[i] = v;
    cursor[i] = v;
  }
  if (i == n) row_ptr[n] = bsum[nb];
}

__global__ void k_fill(const int* __restrict__ dstArr, int* __restrict__ cursor,
                       int* __restrict__ perm, int E, int Et) {
  int i = blockIdx.x * blockDim.x + threadIdx.x;
  if (i >= Et) return;
  int d = (i < E) ? dstArr[i] : (i - E);
  int pos = atomicAdd(&cursor[d], 1);
  perm[pos] = i;
}

// ---------------------------------------------------------------------------
// fp32 -> fp16 conversion, 4 segments in one launch (each n multiple of 4)
// ---------------------------------------------------------------------------
__global__ void k_f2h4(const float* s0, f16* d0, int n0,
                       const float* s1, f16* d1, int n1,
                       const float* s2, f16* d2, int n2,
                       const float* s3, f16* d3, int n3) {
  int i = blockIdx.x * blockDim.x + threadIdx.x;
  const float* s; f16* d;
  if (i < n0) { s = s0; d = d0; }
  else if ((i -= n0) < n1) { s = s1; d = d1; }
  else if ((i -= n1) < n2) { s = s2; d = d2; }
  else if ((i -= n2) < n3) { s = s3; d = d3; }
  else return;
  float4 v = ((const float4*)s)[i];
  union { f16 h[4]; double dd; } u;
  u.h[0] = (f16)v.x; u.h[1] = (f16)v.y; u.h[2] = (f16)v.z; u.h[3] = (f16)v.w;
  ((double*)d)[i] = u.dd;
}

// ---------------------------------------------------------------------------
// HGEMM (fp16 MFMA, fp32 accumulate): C[M,Nn] = A[M,K] @ B[Nn,K]^T
// 128x128 tile, BK=32, 256 thr = 4 waves, wave = 64x64 quadrant (4x4 MFMAs).
// Fused GAT-attention epilogue (block covers one head's 128 cols).
// ---------------------------------------------------------------------------
#define LDSW 40
__global__ __launch_bounds__(256) void k_hgemm_nt(
    const f16* __restrict__ A, const f16* __restrict__ B,
    f16* __restrict__ C, int M, int Nn, int K,
    const float* __restrict__ a_src, const float* __restrict__ a_dst,
    float* __restrict__ sArr, float* __restrict__ dArr,
    unsigned* __restrict__ gmaxU, int H) {
  __shared__ f16 As[128 * LDSW];
  __shared__ f16 Bs[128 * LDSW];
  int tid = threadIdx.x;
  int wave = tid >> 6, lane = tid & 63;
  int quad = lane >> 4, l16 = lane & 15;
  int m0 = blockIdx.y * 128, n0 = blockIdx.x * 128;
  int wm = (wave & 1) * 64, wn = (wave >> 1) * 64;

  int srow = tid >> 2;
  int scol = (tid & 3) * 8;
  int ar0 = m0 + srow;       if (ar0 >= M) ar0 = M - 1;
  int ar1 = m0 + srow + 64;  if (ar1 >= M) ar1 = M - 1;
  const f16* Ap0 = A + (size_t)ar0 * K + scol;
  const f16* Ap1 = A + (size_t)ar1 * K + scol;
  const f16* Bp0 = B + (size_t)(n0 + srow) * K + scol;
  const f16* Bp1 = B + (size_t)(n0 + srow + 64) * K + scol;
  f16* Asw0 = &As[srow * LDSW + scol];
  f16* Asw1 = &As[(srow + 64) * LDSW + scol];
  f16* Bsw0 = &Bs[srow * LDSW + scol];
  f16* Bsw1 = &Bs[(srow + 64) * LDSW + scol];

  const f16* Ard[4];
  const f16* Brd[4];
#pragma unroll
  for (int i = 0; i < 4; ++i) {
    Ard[i] = &As[(wm + i * 16 + l16) * LDSW + quad * 8];
    Brd[i] = &Bs[(wn + i * 16 + l16) * LDSW + quad * 8];
  }

  f32x4 acc[4][4];
#pragma unroll
  for (int i = 0; i < 4; ++i)
#pragma unroll
    for (int j = 0; j < 4; ++j) acc[i][j] = (f32x4)(0.f);

  for (int k0 = 0; k0 < K; k0 += 32) {
    f16x8 av0 = *(const f16x8*)(Ap0 + k0);
    f16x8 av1 = *(const f16x8*)(Ap1 + k0);
    f16x8 bv0 = *(const f16x8*)(Bp0 + k0);
    f16x8 bv1 = *(const f16x8*)(Bp1 + k0);
    __syncthreads();
    *(f16x8*)Asw0 = av0;
    *(f16x8*)Asw1 = av1;
    *(f16x8*)Bsw0 = bv0;
    *(f16x8*)Bsw1 = bv1;
    __syncthreads();
    f16x8 af[4], bf[4];
#pragma unroll
    for (int i = 0; i < 4; ++i) af[i] = *(const f16x8*)Ard[i];
#pragma unroll
    for (int j = 0; j < 4; ++j) bf[j] = *(const f16x8*)Brd[j];
#pragma unroll
    for (int i = 0; i < 4; ++i)
#pragma unroll
      for (int j = 0; j < 4; ++j)
        acc[i][j] = __builtin_amdgcn_mfma_f32_16x16x32_f16(af[i], bf[j], acc[i][j], 0, 0, 0);
  }

  // ---- C store ----
#pragma unroll
  for (int i = 0; i < 4; ++i) {
#pragma unroll
    for (int r = 0; r < 4; ++r) {
      int m = m0 + wm + i * 16 + quad * 4 + r;
      if (m < M) {
        f16* Cp = C + (size_t)m * Nn + n0 + wn + l16;
#pragma unroll
        for (int j = 0; j < 4; ++j) Cp[j * 16] = (f16)acc[i][j][r];
      }
    }
  }

  // ---- fused attention scalars ----
  float av[4], ad[4];
#pragma unroll
  for (int j = 0; j < 4; ++j) {
    int col = n0 + wn + l16 + j * 16;
    av[j] = a_src[col];
    ad[j] = a_dst[col];
  }
  float sp[16], dp[16];
#pragma unroll
  for (int i = 0; i < 4; ++i)
#pragma unroll
    for (int r = 0; r < 4; ++r) {
      float ss = 0.f, dd = 0.f;
#pragma unroll
      for (int j = 0; j < 4; ++j) {
        ss += acc[i][j][r] * av[j];
        dd += acc[i][j][r] * ad[j];
      }
#pragma unroll
      for (int msk = 1; msk < 16; msk <<= 1) {
        ss += __shfl_xor(ss, msk);
        dd += __shfl_xor(dd, msk);
      }
      sp[i * 4 + r] = ss;
      dp[i * 4 + r] = dd;
    }

  __syncthreads();  // done reading As/Bs; reuse as float scratch
  float* fb = (float*)As;
  int wv = wn >> 6;
  if (l16 == 0) {
#pragma unroll
    for (int i = 0; i < 4; ++i)
#pragma unroll
      for (int r = 0; r < 4; ++r) {
        int row = wm + i * 16 + quad * 4 + r;
        fb[wv * 128 + row] = sp[i * 4 + r];
        fb[256 + wv * 128 + row] = dp[i * 4 + r];
      }
  }
  __syncthreads();
  if (tid < 128) {
    int m = m0 + tid;
    if (m < M) {
      float s = fb[tid] + fb[128 + tid];
      float d = fb[256 + tid] + fb[384 + tid];
      int head = n0 >> 7;
      sArr[(size_t)m * H + head] = s;
      dArr[(size_t)m * H + head] = d;
      atomicMax(&gmaxU[head], ordf(s));
    }
  }
}

// ---------------------------------------------------------------------------
// Segment softmax + aggregation: ONE WAVE PER NODE, no barriers, no LDS.
// Shift = leaky(gmax + d_n) >= segment max (leaky monotone; softmax
// shift-invariant). gmax passed as order-preserving uint.
// ---------------------------------------------------------------------------
template <int HH, int CT, bool DOELU, typename OutT>
__global__ __launch_bounds__(256) void k_aggregate(
    const f16* __restrict__ hin, const float* __restrict__ sArr,
    const float* __restrict__ dArr, const int* __restrict__ row_ptr,
    const int* __restrict__ perm, const int* __restrict__ srcArr,
    const unsigned* __restrict__ gmaxU, const float* __restrict__ bias,
    OutT* __restrict__ outp, int N, int E) {
  constexpr int VEC = CT / 64;
  constexpr int CPER = CT / HH;
  using gvec = typename VecT<VEC>::T;

  int n = blockIdx.x * 4 + (threadIdx.x >> 6);
  int lane = threadIdx.x & 63;
  if (n >= N) return;
  int e0 = row_ptr[n];
  int deg = row_ptr[n + 1] - e0;

  float dloc[HH], mn[HH];
#pragma unroll
  for (int h = 0; h < HH; ++h) {
    dloc[h] = dArr[n * HH + h];
    float m = unordf(gmaxU[h]) + dloc[h];
    mn[h] = (m > 0.f) ? m : 0.2f * m;
  }

  const int lanehead = (HH == 1) ? 0 : (lane * VEC) / CPER;
  float acc[VEC];
#pragma unroll
  for (int k = 0; k < VEC; ++k) acc[k] = 0.f;
  float denom[HH];
#pragma unroll
  for (int h = 0; h < HH; ++h) denom[h] = 0.f;

  for (int base = 0; base < deg; base += 64) {
    int cn = min(64, deg - base);
    int s_l = n;
    float w_l[HH];
#pragma unroll
    for (int h = 0; h < HH; ++h) w_l[h] = 0.f;
    if (lane < cn) {
      int eid = perm[e0 + base + lane];
      s_l = (eid < E) ? srcArr[eid] : (eid - E);
      if (HH == 4) {
        float4 sv = ((const float4*)sArr)[s_l];
        float svv[4] = {sv.x, sv.y, sv.z, sv.w};
#pragma unroll
        for (int h = 0; h < 4; ++h) {
          float e = svv[h] + dloc[h];
          e = (e > 0.f) ? e : 0.2f * e;
          w_l[h] = __expf(e - mn[h]);
        }
      } else {
        float e = sArr[s_l] + dloc[0];
        e = (e > 0.f) ? e : 0.2f * e;
        w_l[0] = __expf(e - mn[0]);
      }
    }
    for (int i = 0; i < cn; ++i) {
      int s = __shfl(s_l, i);
      float wh[HH];
#pragma unroll
      for (int h = 0; h < HH; ++h) {
        wh[h] = __shfl(w_l[h], i);
        denom[h] += wh[h];
      }
      float w = wh[lanehead];
      gvec v = *(const gvec*)(hin + (size_t)s * CT + lane * VEC);
#pragma unroll
      for (int k = 0; k < VEC; ++k) acc[k] += w * (float)v[k];
    }
  }

  float dn = denom[lanehead] + 1e-16f;
  struct alignas(sizeof(OutT) * VEC) OutV { OutT v[VEC]; } ov;
#pragma unroll
  for (int k = 0; k < VEC; ++k) {
    float v = acc[k] / dn + bias[lane * VEC + k];
    if (DOELU) v = (v > 0.f) ? v : expm1f(v);
    ov.v[k] = (OutT)v;
  }
  *(OutV*)(outp + (size_t)n * CT + lane * VEC) = ov;
}

// ---------------------------------------------------------------------------
// Allocation head (Wh1 staged in LDS, persistent blocks)
// ---------------------------------------------------------------------------
__global__ __launch_bounds__(256) void k_head(
    const float* __restrict__ emb, const float* __restrict__ Wh1,
    const float* __restrict__ bh1, const float* __restrict__ Wh2,
    const float* __restrict__ bh2, float* __restrict__ scores, int N) {
  __shared__ float w1s[64 * 132];
  __shared__ float w2s[64];
  __shared__ float b1s[64];
  int t = threadIdx.x;
  for (int i = t; i < 64 * 32; i += 256) {
    int r = i >> 5, c4 = i & 31;
    float4 v = ((const float4*)Wh1)[i];
    *(float4*)&w1s[r * 132 + c4 * 4] = v;
  }
  if (t < 64) { w2s[t] = Wh2[t]; b1s[t] = bh1[t]; }
  __syncthreads();
  float b2v = bh2[0];
  int wave = t >> 6, lane = t & 63;
  int gw = blockIdx.x * 4 + wave;
  int nw = gridDim.x * 4;
  for (int n = gw; n < N; n += nw) {
    float2 xv = ((const float2*)(emb + (size_t)n * 128))[lane];
    float z = b1s[lane];
#pragma unroll
    for (int j = 0; j < 32; ++j) {
      float4 w = *(const float4*)&w1s[lane * 132 + 4 * j];
      float a0 = __shfl(xv.x, 2 * j);
      float a1 = __shfl(xv.y, 2 * j);
      float a2 = __shfl(xv.x, 2 * j + 1);
      float a3 = __shfl(xv.y, 2 * j + 1);
      z += w.x * a0 + w.y * a1 + w.z * a2 + w.w * a3;
    }
    z = fmaxf(z, 0.f);
    float v = z * w2s[lane];
#pragma unroll
    for (int off = 32; off; off >>= 1) v += __shfl_down(v, off);
    if (lane == 0) scores[n] = 1.f / (1.f + __expf(-(v + b2v)));
  }
}

// ---------------------------------------------------------------------------

extern "C" void kernel_launch(void* const* d_in, const int* in_sizes, int n_in,
                              void* d_out, int out_size, void* d_ws, size_t ws_size,
                              hipStream_t stream) {
  const float* x   = (const float*)d_in[0];
  const int*   ei  = (const int*)d_in[1];
  const float* W1  = (const float*)d_in[2];
  const float* as1 = (const float*)d_in[3];
  const float* ad1 = (const float*)d_in[4];
  const float* b1  = (const float*)d_in[5];
  const float* W2  = (const float*)d_in[6];
  const float* as2 = (const float*)d_in[7];
  const float* ad2 = (const float*)d_in[8];
  const float* b2  = (const float*)d_in[9];
  const float* W3  = (const float*)d_in[10];
  const float* as3 = (const float*)d_in[11];
  const float* ad3 = (const float*)d_in[12];
  const float* b3  = (const float*)d_in[13];
  const float* Wh1 = (const float*)d_in[14];
  const float* bh1 = (const float*)d_in[15];
  const float* Wh2 = (const float*)d_in[16];
  const float* bh2 = (const float*)d_in[17];
  float* out = (float*)d_out;

  const int F = 256, HC = 512, H = 4, C = 128;
  const int N = in_sizes[0] / F;
  const int E = in_sizes[1] / 2;
  const int Et = E + N;
  const int* srcArr = ei;
  const int* dstArr = ei + E;

  char* ws = (char*)d_ws;
  size_t off = 0;
  auto alloc = [&](size_t bytes) -> void* {
    void* p = ws + off;
    off += (bytes + 255) & ~(size_t)255;
    return p;
  };
  f16*   h16    = (f16*)alloc((size_t)N * HC * 2);
  f16*   hAgg   = (f16*)alloc((size_t)N * HC * 2);
  f16*   xh     = (f16*)alloc((size_t)N * F * 2);
  f16*   W1h    = (f16*)alloc((size_t)HC * F * 2);
  f16*   W2h    = (f16*)alloc((size_t)HC * HC * 2);
  f16*   W3h    = (f16*)alloc((size_t)C * HC * 2);
  int* row_ptr  = (int*)alloc((size_t)(N + 1) * 4);
  // zero region: cnt (N ints) + 3x4 gmax uints, one memset
  char* zr      = (char*)alloc((size_t)N * 4 + 64);
  int* cnt      = (int*)zr;
  unsigned* gm1 = (unsigned*)(zr + (size_t)N * 4);
  unsigned* gm2 = gm1 + 4;
  unsigned* gm3 = gm1 + 8;
  int* cursor   = (int*)alloc((size_t)N * 4);
  int* perm     = (int*)alloc((size_t)Et * 4);
  float* sArr   = (float*)alloc((size_t)N * H * 4);
  float* dArr   = (float*)alloc((size_t)N * H * 4);
  int* bsum     = (int*)alloc((size_t)1028 * 4);
  (void)ws_size; (void)n_in; (void)out_size;

  // ---- CSR build ----
  hipMemsetAsync(zr, 0, (size_t)N * 4 + 64, stream);
  int eb = (Et + 255) / 256;
  int nb = (N + 1023) / 1024;
  k_count<<<eb, 256, 0, stream>>>(dstArr, cnt, E, Et);
  k_scanA<<<nb, 256, 0, stream>>>(cnt, row_ptr, bsum, N);
  k_scanB<<<1, 1024, 0, stream>>>(bsum, nb);
  k_scanC<<<(N + 256) / 256, 256, 0, stream>>>(row_ptr, cursor, bsum, N, nb);
  k_fill<<<eb, 256, 0, stream>>>(dstArr, cursor, perm, E, Et);

  // ---- fp16 conversions (one launch) ----
  int c0 = N * F / 4, c1 = HC * F / 4, c2 = HC * HC / 4, c3 = C * HC / 4;
  int ctot = c0 + c1 + c2 + c3;
  k_f2h4<<<(ctot + 255) / 256, 256, 0, stream>>>(x, xh, c0, W1, W1h, c1,
                                                 W2, W2h, c2, W3, W3h, c3);

  int aggGrid = (N + 3) / 4;
  dim3 g1(HC / 128, (N + 127) / 128);
  dim3 g3(C / 128, (N + 127) / 128);

  // ---- layer 1: F -> H*C, elu ----
  k_hgemm_nt<<<g1, 256, 0, stream>>>(xh, W1h, h16, N, HC, F,
                                     as1, ad1, sArr, dArr, gm1, H);
  k_aggregate<4, 512, true, f16><<<aggGrid, 256, 0, stream>>>(
      h16, sArr, dArr, row_ptr, perm, srcArr, gm1, b1, hAgg, N, E);

  // ---- layer 2: H*C -> H*C, elu ----
  k_hgemm_nt<<<g1, 256, 0, stream>>>(hAgg, W2h, h16, N, HC, HC,
                                     as2, ad2, sArr, dArr, gm2, H);
  k_aggregate<4, 512, true, f16><<<aggGrid, 256, 0, stream>>>(
      h16, sArr, dArr, row_ptr, perm, srcArr, gm2, b2, hAgg, N, E);

  // ---- layer 3: H*C -> C, single head, no concat/elu -> embeddings ----
  k_hgemm_nt<<<g3, 256, 0, stream>>>(hAgg, W3h, h16, N, C, HC,
                                     as3, ad3, sArr, dArr, gm3, 1);
  k_aggregate<1, 128, false, float><<<aggGrid, 256, 0, stream>>>(
      h16, sArr, dArr, row_ptr, perm, srcArr, gm3, b3, out, N, E);

  // ---- allocation head ----
  k_head<<<512, 256, 0, stream>>>(out, Wh1, bh1, Wh2, bh2, out + (size_t)N * C, N);
}

// Round 9
// 841.714 us; speedup vs baseline: 1.2692x; 1.0236x over previous
//
#include <hip/hip_runtime.h>
#include <math.h>

typedef _Float16 f16;
typedef f16 f16x2 __attribute__((ext_vector_type(2)));
typedef f16 f16x8 __attribute__((ext_vector_type(8)));
typedef float f32x4 __attribute__((ext_vector_type(4)));

template <int V> struct VecT;
template <> struct VecT<2> { using T = f16 __attribute__((ext_vector_type(2))); };
template <> struct VecT<8> { using T = f16 __attribute__((ext_vector_type(8))); };

__device__ __forceinline__ unsigned ordf(float f) {
  unsigned u = __float_as_uint(f);
  return (u >> 31) ? ~u : (u | 0x80000000u);
}
__device__ __forceinline__ float unordf(unsigned u) {
  return (u >> 31) ? __uint_as_float(u & 0x7fffffffu) : __uint_as_float(~u);
}

// ---------------------------------------------------------------------------
// CSR build: histogram of dst -> 3-stage parallel scan -> fill permutation
// Edge id space: [0, E) = real edges, [E, E+N) = self loops (src=dst=id-E)
// ---------------------------------------------------------------------------

__global__ void k_count(const int* __restrict__ dstArr, int* __restrict__ cnt,
                        int E, int Et) {
  int i = blockIdx.x * blockDim.x + threadIdx.x;
  if (i >= Et) return;
  int d = (i < E) ? dstArr[i] : (i - E);
  atomicAdd(&cnt[d], 1);
}

__global__ __launch_bounds__(256) void k_scanA(const int* __restrict__ cnt,
                                               int* __restrict__ row_ptr,
                                               int* __restrict__ bsum, int n) {
  __shared__ int part[256];
  int t = threadIdx.x;
  int base = blockIdx.x * 1024 + t * 4;
  int4 v = make_int4(0, 0, 0, 0);
  if (base + 3 < n) v = *(const int4*)&cnt[base];
  else {
    if (base + 0 < n) v.x = cnt[base + 0];
    if (base + 1 < n) v.y = cnt[base + 1];
    if (base + 2 < n) v.z = cnt[base + 2];
    if (base + 3 < n) v.w = cnt[base + 3];
  }
  int s = v.x + v.y + v.z + v.w;
  part[t] = s;
  __syncthreads();
  for (int off = 1; off < 256; off <<= 1) {
    int x = (t >= off) ? part[t - off] : 0;
    __syncthreads();
    part[t] += x;
    __syncthreads();
  }
  int p0 = (t == 0) ? 0 : part[t - 1];
  int p1 = p0 + v.x, p2 = p1 + v.y, p3 = p2 + v.z;
  if (base + 0 < n) row_ptr[base + 0] = p0;
  if (base + 1 < n) row_ptr[base + 1] = p1;
  if (base + 2 < n) row_ptr[base + 2] = p2;
  if (base + 3 < n) row_ptr[base + 3] = p3;
  if (t == 255) bsum[blockIdx.x] = part[255];
}

__global__ __launch_bounds__(1024) void k_scanB(int* __restrict__ bsum, int nb) {
  __shared__ int part[1024];
  int t = threadIdx.x;
  int v = (t < nb) ? bsum[t] : 0;
  part[t] = v;
  __syncthreads();
  for (int off = 1; off < 1024; off <<= 1) {
    int x = (t >= off) ? part[t - off] : 0;
    __syncthreads();
    part[t] += x;
    __syncthreads();
  }
  if (t < nb) bsum[t] = (t == 0) ? 0 : part[t - 1];
  if (t == 1023) bsum[nb] = part[1023];
}

__global__ void k_scanC(int* __restrict__ row_ptr, int* __restrict__ cursor,
                        const int* __restrict__ bsum, int n, int nb) {
  int i = blockIdx.x * blockDim.x + threadIdx.x;
  if (i < n) {
    int v = row_ptr[i] + bsum[i >> 10];
    row_ptr[i] = v;
    cursor[i] = v;
  }
  if (i == n) row_ptr[n] = bsum[nb];
}

__global__ void k_fill(const int* __restrict__ dstArr, int* __restrict__ cursor,
                       int* __restrict__ perm, int E, int Et) {
  int i = blockIdx.x * blockDim.x + threadIdx.x;
  if (i >= Et) return;
  int d = (i < E) ? dstArr[i] : (i - E);
  int pos = atomicAdd(&cursor[d], 1);
  perm[pos] = i;
}

// ---------------------------------------------------------------------------
// fp32 -> fp16 conversion, 4 segments in one launch (each n multiple of 4)
// ---------------------------------------------------------------------------
__global__ void k_f2h4(const float* s0, f16* d0, int n0,
                       const float* s1, f16* d1, int n1,
                       const float* s2, f16* d2, int n2,
                       const float* s3, f16* d3, int n3) {
  int i = blockIdx.x * blockDim.x + threadIdx.x;
  const float* s; f16* d;
  if (i < n0) { s = s0; d = d0; }
  else if ((i -= n0) < n1) { s = s1; d = d1; }
  else if ((i -= n1) < n2) { s = s2; d = d2; }
  else if ((i -= n2) < n3) { s = s3; d = d3; }
  else return;
  float4 v = ((const float4*)s)[i];
  union { f16 h[4]; double dd; } u;
  u.h[0] = (f16)v.x; u.h[1] = (f16)v.y; u.h[2] = (f16)v.z; u.h[3] = (f16)v.w;
  ((double*)d)[i] = u.dd;
}

// ---------------------------------------------------------------------------
// HGEMM (fp16 MFMA, fp32 accumulate): C[M,Nn] = A[M,K] @ B[Nn,K]^T
// 128x128 tile, BK=32, 256 thr = 4 waves, wave = 64x64 quadrant (4x4 MFMAs).
// Staging via global_load_lds width=16 (async direct-to-LDS). LDS layout:
// natural stride 32 f16 (64 B/row) with xor chunk swizzle
//   chunk_lds = chunk_glob ^ ((row>>1)&3)
// -> write side matches the wave-uniform-base+lane*16 landing pattern,
//    read side spreads 64 b128 lanes over all 8 bank groups (2-way, free).
// Fused GAT-attention epilogue (block covers one head's 128 cols).
// ---------------------------------------------------------------------------
__global__ __launch_bounds__(256) void k_hgemm_nt(
    const f16* __restrict__ A, const f16* __restrict__ B,
    f16* __restrict__ C, int M, int Nn, int K,
    const float* __restrict__ a_src, const float* __restrict__ a_dst,
    float* __restrict__ sArr, float* __restrict__ dArr,
    unsigned* __restrict__ gmaxU, int H) {
  __shared__ f16 As[128 * 32];
  __shared__ f16 Bs[128 * 32];
  int tid = threadIdx.x;
  int wave = tid >> 6, lane = tid & 63;
  int quad = lane >> 4, l16 = lane & 15;
  int m0 = blockIdx.y * 128, n0 = blockIdx.x * 128;
  int wm = (wave & 1) * 64, wn = (wave >> 1) * 64;

  // ---- staging addresses (wave w stages rows w*16.. and 64+w*16.. of A and B)
  int lr = lane >> 2;            // row within 16-row group
  int lc = lane & 3;             // lds chunk slot this lane fills
  int chunk = lc ^ ((lr >> 1) & 3);  // global chunk to fetch (swizzle)
  int rb0 = wave * 16;
  int rb1 = 64 + wave * 16;
  int ga0 = m0 + rb0 + lr; if (ga0 >= M) ga0 = M - 1;
  int ga1 = m0 + rb1 + lr; if (ga1 >= M) ga1 = M - 1;
  const f16* gA0 = A + (size_t)ga0 * K + chunk * 8;
  const f16* gA1 = A + (size_t)ga1 * K + chunk * 8;
  const f16* gB0 = B + (size_t)(n0 + rb0 + lr) * K + chunk * 8;
  const f16* gB1 = B + (size_t)(n0 + rb1 + lr) * K + chunk * 8;
  f16* lA0 = &As[rb0 * 32];
  f16* lA1 = &As[rb1 * 32];
  f16* lB0 = &Bs[rb0 * 32];
  f16* lB1 = &Bs[rb1 * 32];

  // ---- fragment read pointers (chunk = quad ^ ((l16>>1)&3))
  int rsw = (quad ^ ((l16 >> 1) & 3)) * 8;
  const f16* Ard[4];
  const f16* Brd[4];
#pragma unroll
  for (int i = 0; i < 4; ++i) {
    Ard[i] = &As[(wm + i * 16 + l16) * 32 + rsw];
    Brd[i] = &Bs[(wn + i * 16 + l16) * 32 + rsw];
  }

  f32x4 acc[4][4];
#pragma unroll
  for (int i = 0; i < 4; ++i)
#pragma unroll
    for (int j = 0; j < 4; ++j) acc[i][j] = (f32x4)(0.f);

  for (int k0 = 0; k0 < K; k0 += 32) {
    __syncthreads();  // previous iteration's LDS reads complete
    __builtin_amdgcn_global_load_lds(
        (const __attribute__((address_space(1))) void*)(gA0 + k0),
        (__attribute__((address_space(3))) void*)lA0, 16, 0, 0);
    __builtin_amdgcn_global_load_lds(
        (const __attribute__((address_space(1))) void*)(gA1 + k0),
        (__attribute__((address_space(3))) void*)lA1, 16, 0, 0);
    __builtin_amdgcn_global_load_lds(
        (const __attribute__((address_space(1))) void*)(gB0 + k0),
        (__attribute__((address_space(3))) void*)lB0, 16, 0, 0);
    __builtin_amdgcn_global_load_lds(
        (const __attribute__((address_space(1))) void*)(gB1 + k0),
        (__attribute__((address_space(3))) void*)lB1, 16, 0, 0);
    __syncthreads();  // drains vmcnt -> staged tile visible to all waves
    f16x8 af[4], bf[4];
#pragma unroll
    for (int i = 0; i < 4; ++i) af[i] = *(const f16x8*)Ard[i];
#pragma unroll
    for (int j = 0; j < 4; ++j) bf[j] = *(const f16x8*)Brd[j];
#pragma unroll
    for (int i = 0; i < 4; ++i)
#pragma unroll
      for (int j = 0; j < 4; ++j)
        acc[i][j] = __builtin_amdgcn_mfma_f32_16x16x32_f16(af[i], bf[j], acc[i][j], 0, 0, 0);
  }

  // ---- C store ----
#pragma unroll
  for (int i = 0; i < 4; ++i) {
#pragma unroll
    for (int r = 0; r < 4; ++r) {
      int m = m0 + wm + i * 16 + quad * 4 + r;
      if (m < M) {
        f16* Cp = C + (size_t)m * Nn + n0 + wn + l16;
#pragma unroll
        for (int j = 0; j < 4; ++j) Cp[j * 16] = (f16)acc[i][j][r];
      }
    }
  }

  // ---- fused attention scalars ----
  float av[4], ad[4];
#pragma unroll
  for (int j = 0; j < 4; ++j) {
    int col = n0 + wn + l16 + j * 16;
    av[j] = a_src[col];
    ad[j] = a_dst[col];
  }
  float sp[16], dp[16];
#pragma unroll
  for (int i = 0; i < 4; ++i)
#pragma unroll
    for (int r = 0; r < 4; ++r) {
      float ss = 0.f, dd = 0.f;
#pragma unroll
      for (int j = 0; j < 4; ++j) {
        ss += acc[i][j][r] * av[j];
        dd += acc[i][j][r] * ad[j];
      }
#pragma unroll
      for (int msk = 1; msk < 16; msk <<= 1) {
        ss += __shfl_xor(ss, msk);
        dd += __shfl_xor(dd, msk);
      }
      sp[i * 4 + r] = ss;
      dp[i * 4 + r] = dd;
    }

  __syncthreads();  // done reading As/Bs; reuse as float scratch
  float* fb = (float*)As;
  int wv = wn >> 6;
  if (l16 == 0) {
#pragma unroll
    for (int i = 0; i < 4; ++i)
#pragma unroll
      for (int r = 0; r < 4; ++r) {
        int row = wm + i * 16 + quad * 4 + r;
        fb[wv * 128 + row] = sp[i * 4 + r];
        fb[256 + wv * 128 + row] = dp[i * 4 + r];
      }
  }
  __syncthreads();
  if (tid < 128) {
    int m = m0 + tid;
    if (m < M) {
      float s = fb[tid] + fb[128 + tid];
      float d = fb[256 + tid] + fb[384 + tid];
      int head = n0 >> 7;
      sArr[(size_t)m * H + head] = s;
      dArr[(size_t)m * H + head] = d;
      atomicMax(&gmaxU[head], ordf(s));
    }
  }
}

// ---------------------------------------------------------------------------
// Segment softmax + aggregation: ONE WAVE PER NODE, no barriers, no LDS.
// Shift = leaky(gmax + d_n) >= segment max (leaky monotone; softmax
// shift-invariant). gmax passed as order-preserving uint.
// ---------------------------------------------------------------------------
template <int HH, int CT, bool DOELU, typename OutT>
__global__ __launch_bounds__(256) void k_aggregate(
    const f16* __restrict__ hin, const float* __restrict__ sArr,
    const float* __restrict__ dArr, const int* __restrict__ row_ptr,
    const int* __restrict__ perm, const int* __restrict__ srcArr,
    const unsigned* __restrict__ gmaxU, const float* __restrict__ bias,
    OutT* __restrict__ outp, int N, int E) {
  constexpr int VEC = CT / 64;
  constexpr int CPER = CT / HH;
  using gvec = typename VecT<VEC>::T;

  int n = blockIdx.x * 4 + (threadIdx.x >> 6);
  int lane = threadIdx.x & 63;
  if (n >= N) return;
  int e0 = row_ptr[n];
  int deg = row_ptr[n + 1] - e0;

  float dloc[HH], mn[HH];
#pragma unroll
  for (int h = 0; h < HH; ++h) {
    dloc[h] = dArr[n * HH + h];
    float m = unordf(gmaxU[h]) + dloc[h];
    mn[h] = (m > 0.f) ? m : 0.2f * m;
  }

  const int lanehead = (HH == 1) ? 0 : (lane * VEC) / CPER;
  float acc[VEC];
#pragma unroll
  for (int k = 0; k < VEC; ++k) acc[k] = 0.f;
  float denom[HH];
#pragma unroll
  for (int h = 0; h < HH; ++h) denom[h] = 0.f;

  for (int base = 0; base < deg; base += 64) {
    int cn = min(64, deg - base);
    int s_l = n;
    float w_l[HH];
#pragma unroll
    for (int h = 0; h < HH; ++h) w_l[h] = 0.f;
    if (lane < cn) {
      int eid = perm[e0 + base + lane];
      s_l = (eid < E) ? srcArr[eid] : (eid - E);
      if (HH == 4) {
        float4 sv = ((const float4*)sArr)[s_l];
        float svv[4] = {sv.x, sv.y, sv.z, sv.w};
#pragma unroll
        for (int h = 0; h < 4; ++h) {
          float e = svv[h] + dloc[h];
          e = (e > 0.f) ? e : 0.2f * e;
          w_l[h] = __expf(e - mn[h]);
        }
      } else {
        float e = sArr[s_l] + dloc[0];
        e = (e > 0.f) ? e : 0.2f * e;
        w_l[0] = __expf(e - mn[0]);
      }
    }
    for (int i = 0; i < cn; ++i) {
      int s = __shfl(s_l, i);
      float wh[HH];
#pragma unroll
      for (int h = 0; h < HH; ++h) {
        wh[h] = __shfl(w_l[h], i);
        denom[h] += wh[h];
      }
      float w = wh[lanehead];
      gvec v = *(const gvec*)(hin + (size_t)s * CT + lane * VEC);
#pragma unroll
      for (int k = 0; k < VEC; ++k) acc[k] += w * (float)v[k];
    }
  }

  float dn = denom[lanehead] + 1e-16f;
  struct alignas(sizeof(OutT) * VEC) OutV { OutT v[VEC]; } ov;
#pragma unroll
  for (int k = 0; k < VEC; ++k) {
    float v = acc[k] / dn + bias[lane * VEC + k];
    if (DOELU) v = (v > 0.f) ? v : expm1f(v);
    ov.v[k] = (OutT)v;
  }
  *(OutV*)(outp + (size_t)n * CT + lane * VEC) = ov;
}

// ---------------------------------------------------------------------------
// Allocation head (Wh1 staged in LDS, persistent blocks)
// ---------------------------------------------------------------------------
__global__ __launch_bounds__(256) void k_head(
    const float* __restrict__ emb, const float* __restrict__ Wh1,
    const float* __restrict__ bh1, const float* __restrict__ Wh2,
    const float* __restrict__ bh2, float* __restrict__ scores, int N) {
  __shared__ float w1s[64 * 132];
  __shared__ float w2s[64];
  __shared__ float b1s[64];
  int t = threadIdx.x;
  for (int i = t; i < 64 * 32; i += 256) {
    int r = i >> 5, c4 = i & 31;
    float4 v = ((const float4*)Wh1)[i];
    *(float4*)&w1s[r * 132 + c4 * 4] = v;
  }
  if (t < 64) { w2s[t] = Wh2[t]; b1s[t] = bh1[t]; }
  __syncthreads();
  float b2v = bh2[0];
  int wave = t >> 6, lane = t & 63;
  int gw = blockIdx.x * 4 + wave;
  int nw = gridDim.x * 4;
  for (int n = gw; n < N; n += nw) {
    float2 xv = ((const float2*)(emb + (size_t)n * 128))[lane];
    float z = b1s[lane];
#pragma unroll
    for (int j = 0; j < 32; ++j) {
      float4 w = *(const float4*)&w1s[lane * 132 + 4 * j];
      float a0 = __shfl(xv.x, 2 * j);
      float a1 = __shfl(xv.y, 2 * j);
      float a2 = __shfl(xv.x, 2 * j + 1);
      float a3 = __shfl(xv.y, 2 * j + 1);
      z += w.x * a0 + w.y * a1 + w.z * a2 + w.w * a3;
    }
    z = fmaxf(z, 0.f);
    float v = z * w2s[lane];
#pragma unroll
    for (int off = 32; off; off >>= 1) v += __shfl_down(v, off);
    if (lane == 0) scores[n] = 1.f / (1.f + __expf(-(v + b2v)));
  }
}

// ---------------------------------------------------------------------------

extern "C" void kernel_launch(void* const* d_in, const int* in_sizes, int n_in,
                              void* d_out, int out_size, void* d_ws, size_t ws_size,
                              hipStream_t stream) {
  const float* x   = (const float*)d_in[0];
  const int*   ei  = (const int*)d_in[1];
  const float* W1  = (const float*)d_in[2];
  const float* as1 = (const float*)d_in[3];
  const float* ad1 = (const float*)d_in[4];
  const float* b1  = (const float*)d_in[5];
  const float* W2  = (const float*)d_in[6];
  const float* as2 = (const float*)d_in[7];
  const float* ad2 = (const float*)d_in[8];
  const float* b2  = (const float*)d_in[9];
  const float* W3  = (const float*)d_in[10];
  const float* as3 = (const float*)d_in[11];
  const float* ad3 = (const float*)d_in[12];
  const float* b3  = (const float*)d_in[13];
  const float* Wh1 = (const float*)d_in[14];
  const float* bh1 = (const float*)d_in[15];
  const float* Wh2 = (const float*)d_in[16];
  const float* bh2 = (const float*)d_in[17];
  float* out = (float*)d_out;

  const int F = 256, HC = 512, H = 4, C = 128;
  const int N = in_sizes[0] / F;
  const int E = in_sizes[1] / 2;
  const int Et = E + N;
  const int* srcArr = ei;
  const int* dstArr = ei + E;

  char* ws = (char*)d_ws;
  size_t off = 0;
  auto alloc = [&](size_t bytes) -> void* {
    void* p = ws + off;
    off += (bytes + 255) & ~(size_t)255;
    return p;
  };
  f16*   h16    = (f16*)alloc((size_t)N * HC * 2);
  f16*   hAgg   = (f16*)alloc((size_t)N * HC * 2);
  f16*   xh     = (f16*)alloc((size_t)N * F * 2);
  f16*   W1h    = (f16*)alloc((size_t)HC * F * 2);
  f16*   W2h    = (f16*)alloc((size_t)HC * HC * 2);
  f16*   W3h    = (f16*)alloc((size_t)C * HC * 2);
  int* row_ptr  = (int*)alloc((size_t)(N + 1) * 4);
  // zero region: cnt (N ints) + 3x4 gmax uints, one memset
  char* zr      = (char*)alloc((size_t)N * 4 + 64);
  int* cnt      = (int*)zr;
  unsigned* gm1 = (unsigned*)(zr + (size_t)N * 4);
  unsigned* gm2 = gm1 + 4;
  unsigned* gm3 = gm1 + 8;
  int* cursor   = (int*)alloc((size_t)N * 4);
  int* perm     = (int*)alloc((size_t)Et * 4);
  float* sArr   = (float*)alloc((size_t)N * H * 4);
  float* dArr   = (float*)alloc((size_t)N * H * 4);
  int* bsum     = (int*)alloc((size_t)1028 * 4);
  (void)ws_size; (void)n_in; (void)out_size;

  // ---- CSR build ----
  hipMemsetAsync(zr, 0, (size_t)N * 4 + 64, stream);
  int eb = (Et + 255) / 256;
  int nb = (N + 1023) / 1024;
  k_count<<<eb, 256, 0, stream>>>(dstArr, cnt, E, Et);
  k_scanA<<<nb, 256, 0, stream>>>(cnt, row_ptr, bsum, N);
  k_scanB<<<1, 1024, 0, stream>>>(bsum, nb);
  k_scanC<<<(N + 256) / 256, 256, 0, stream>>>(row_ptr, cursor, bsum, N, nb);
  k_fill<<<eb, 256, 0, stream>>>(dstArr, cursor, perm, E, Et);

  // ---- fp16 conversions (one launch) ----
  int c0 = N * F / 4, c1 = HC * F / 4, c2 = HC * HC / 4, c3 = C * HC / 4;
  int ctot = c0 + c1 + c2 + c3;
  k_f2h4<<<(ctot + 255) / 256, 256, 0, stream>>>(x, xh, c0, W1, W1h, c1,
                                                 W2, W2h, c2, W3, W3h, c3);

  int aggGrid = (N + 3) / 4;
  dim3 g1(HC / 128, (N + 127) / 128);
  dim3 g3(C / 128, (N + 127) / 128);

  // ---- layer 1: F -> H*C, elu ----
  k_hgemm_nt<<<g1, 256, 0, stream>>>(xh, W1h, h16, N, HC, F,
                                     as1, ad1, sArr, dArr, gm1, H);
  k_aggregate<4, 512, true, f16><<<aggGrid, 256, 0, stream>>>(
      h16, sArr, dArr, row_ptr, perm, srcArr, gm1, b1, hAgg, N, E);

  // ---- layer 2: H*C -> H*C, elu ----
  k_hgemm_nt<<<g1, 256, 0, stream>>>(hAgg, W2h, h16, N, HC, HC,
                                     as2, ad2, sArr, dArr, gm2, H);
  k_aggregate<4, 512, true, f16><<<aggGrid, 256, 0, stream>>>(
      h16, sArr, dArr, row_ptr, perm, srcArr, gm2, b2, hAgg, N, E);

  // ---- layer 3: H*C -> C, single head, no concat/elu -> embeddings ----
  k_hgemm_nt<<<g3, 256, 0, stream>>>(hAgg, W3h, h16, N, C, HC,
                                     as3, ad3, sArr, dArr, gm3, 1);
  k_aggregate<1, 128, false, float><<<aggGrid, 256, 0, stream>>>(
      h16, sArr, dArr, row_ptr, perm, srcArr, gm3, b3, out, N, E);

  // ---- allocation head ----
  k_head<<<512, 256, 0, stream>>>(out, Wh1, bh1, Wh2, bh2, out + (size_t)N * C, N);
}